// Round 5
// baseline (652.963 us; speedup 1.0000x reference)
//
#include <hip/hip_runtime.h>
#include <hip/hip_bf16.h>
#include <hip/hip_fp16.h>

#define IN_DIM 128
#define HID    64
#define OUT_DIM 40

// ---------------- degree count ----------------
__global__ void count_k(const int* __restrict__ dst, int e, int* __restrict__ cnt) {
    int i = blockIdx.x * blockDim.x + threadIdx.x;
    if (i < e) atomicAdd(&cnt[dst[i]], 1);
}

__global__ void dinv_k(const int* __restrict__ cnt, float* __restrict__ dinv, int n) {
    int i = blockIdx.x * blockDim.x + threadIdx.x;
    if (i < n) dinv[i] = rsqrtf((float)cnt[i] + 1.0f);
}

// ---------------- hierarchical exclusive scan ----------------
__global__ void scan_local(const int* __restrict__ cnt, int n,
                           int* __restrict__ off, int* __restrict__ bsum) {
    __shared__ int tmp[256];
    int t = threadIdx.x;
    int i0 = blockIdx.x * 1024 + t * 4;
    int c0 = (i0 + 0 < n) ? cnt[i0 + 0] : 0;
    int c1 = (i0 + 1 < n) ? cnt[i0 + 1] : 0;
    int c2 = (i0 + 2 < n) ? cnt[i0 + 2] : 0;
    int c3 = (i0 + 3 < n) ? cnt[i0 + 3] : 0;
    int s = c0 + c1 + c2 + c3;
    tmp[t] = s;
    __syncthreads();
    for (int ofs = 1; ofs < 256; ofs <<= 1) {
        int add = (t >= ofs) ? tmp[t - ofs] : 0;
        __syncthreads();
        tmp[t] += add;
        __syncthreads();
    }
    int run = tmp[t] - s;
    if (i0 + 0 < n) off[i0 + 0] = run; run += c0;
    if (i0 + 1 < n) off[i0 + 1] = run; run += c1;
    if (i0 + 2 < n) off[i0 + 2] = run; run += c2;
    if (i0 + 3 < n) off[i0 + 3] = run;
    if (t == 255) bsum[blockIdx.x] = tmp[255];
}

__global__ void scan_bsum(int* __restrict__ bsum, int nb, int n, int* __restrict__ off) {
    __shared__ int tmp[1024];
    int t = threadIdx.x;
    int v = (t < nb) ? bsum[t] : 0;
    tmp[t] = v;
    __syncthreads();
    for (int ofs = 1; ofs < 1024; ofs <<= 1) {
        int add = (t >= ofs) ? tmp[t - ofs] : 0;
        __syncthreads();
        tmp[t] += add;
        __syncthreads();
    }
    if (t < nb) bsum[t] = tmp[t] - v;
    if (t == 1023) off[n] = tmp[1023];
}

__global__ void scan_add(int* __restrict__ off, const int* __restrict__ bsum,
                         int n, int* __restrict__ cursor) {
    int i = blockIdx.x * blockDim.x + threadIdx.x;
    if (i < n) {
        int v = off[i] + bsum[i >> 10];
        off[i] = v;
        cursor[i] = v;
    }
}

__global__ void bin_k(const int* __restrict__ src, const int* __restrict__ dst, int e,
                      int* __restrict__ cursor, int* __restrict__ sorted) {
    int i = blockIdx.x * blockDim.x + threadIdx.x;
    if (i < e) {
        int d = dst[i];
        int pos = atomicAdd(&cursor[d], 1);
        sorted[pos] = src[i];
    }
}

// ---------------- GEMM1: hw1 = fp16(x @ W1), register-blocked ----------------
// 256 threads, tile 32 rows x 64 cols; thread = (col, rowgroup of 8)
__global__ __launch_bounds__(256) void gemm1(const float* __restrict__ x,
                                             const float* __restrict__ W1,
                                             __half* __restrict__ hw1, int n) {
    __shared__ float Ws[IN_DIM][HID];    // 32 KB, [k][col]
    __shared__ float xs[32][IN_DIM];     // 16 KB, [r][k]
    int tid = threadIdx.x;
    // stage W1 (coalesced float4)
    for (int i = tid * 4; i < IN_DIM * HID; i += 256 * 4)
        *(float4*)&Ws[0][i] = *(const float4*)&W1[i];
    // stage x tile (coalesced float4)
    int base = blockIdx.x * 32;
    for (int i = tid; i < 32 * IN_DIM / 4; i += 256) {
        int r = i >> 5, kk = i & 31;          // IN_DIM/4 = 32
        int gr = base + r;
        float4 v = {0.f, 0.f, 0.f, 0.f};
        if (gr < n) v = *(const float4*)&x[(size_t)gr * IN_DIM + kk * 4];
        *(float4*)&xs[r][kk * 4] = v;
    }
    __syncthreads();
    int col = tid & 63;
    int rg  = (tid >> 6) * 8;                 // 4 waves x 8 rows = 32 rows
    float acc[8] = {};
    for (int k = 0; k < IN_DIM; k += 4) {
        float w0 = Ws[k + 0][col], w1 = Ws[k + 1][col];
        float w2 = Ws[k + 2][col], w3 = Ws[k + 3][col];
#pragma unroll
        for (int r = 0; r < 8; ++r) {
            float4 xv = *(float4*)&xs[rg + r][k];   // wave-uniform broadcast
            acc[r] = fmaf(xv.x, w0, acc[r]);
            acc[r] = fmaf(xv.y, w1, acc[r]);
            acc[r] = fmaf(xv.z, w2, acc[r]);
            acc[r] = fmaf(xv.w, w3, acc[r]);
        }
    }
#pragma unroll
    for (int r = 0; r < 8; ++r) {
        int gr = base + rg + r;
        if (gr < n) hw1[(size_t)gr * HID + col] = __float2half(acc[r]);
    }
}

// ---------------- gather1: agg[d] = dinv^2*hw1[d] + sum norm*hw1[src] ----------
__global__ void gather1(const __half* __restrict__ hw1, const float* __restrict__ dinv,
                        const int* __restrict__ off, const int* __restrict__ sorted,
                        float* __restrict__ agg, int n) {
    int wid  = blockIdx.x * (blockDim.x >> 6) + (threadIdx.x >> 6);
    int lane = threadIdx.x & 63;
    if (wid >= n) return;
    float dd = dinv[wid];
    float acc = dd * dd * __half2float(hw1[(size_t)wid * HID + lane]);
    int j = off[wid], en = off[wid + 1];
    for (; j + 4 <= en; j += 4) {
        int s0 = sorted[j + 0], s1 = sorted[j + 1];
        int s2 = sorted[j + 2], s3 = sorted[j + 3];
        float w0 = dinv[s0], w1 = dinv[s1], w2 = dinv[s2], w3 = dinv[s3];
        float v0 = __half2float(hw1[(size_t)s0 * HID + lane]);
        float v1 = __half2float(hw1[(size_t)s1 * HID + lane]);
        float v2 = __half2float(hw1[(size_t)s2 * HID + lane]);
        float v3 = __half2float(hw1[(size_t)s3 * HID + lane]);
        acc = fmaf(dd * w0, v0, acc);
        acc = fmaf(dd * w1, v1, acc);
        acc = fmaf(dd * w2, v2, acc);
        acc = fmaf(dd * w3, v3, acc);
    }
    for (; j < en; ++j) {
        int s = sorted[j];
        acc = fmaf(dd * dinv[s], __half2float(hw1[(size_t)s * HID + lane]), acc);
    }
    agg[(size_t)wid * HID + lane] = acc;
}

// ---------------- GEMM2: hw2 = fp16(relu(h + b1) @ W2), register-blocked -------
// 320 threads, tile 64 rows x 40 cols; thread = (col, rowgroup of 8)
__global__ __launch_bounds__(320) void gemm2(const float* __restrict__ h,
                                             const float* __restrict__ W2,
                                             const float* __restrict__ b1,
                                             __half* __restrict__ hw2, int n) {
    __shared__ float Ws[HID][OUT_DIM];   // 10 KB, [k][col]
    __shared__ float hs[64][HID];        // 16 KB, [r][k]
    int tid = threadIdx.x;
    for (int i = tid; i < HID * OUT_DIM; i += 320) Ws[0][i] = W2[i];
    int base = blockIdx.x * 64;
    for (int i = tid; i < 64 * HID / 4; i += 320) {
        int r = i >> 4, kk = i & 15;          // HID/4 = 16
        int gr = base + r;
        float4 v = {0.f, 0.f, 0.f, 0.f};
        if (gr < n) {
            v = *(const float4*)&h[(size_t)gr * HID + kk * 4];
            v.x = fmaxf(v.x + b1[kk * 4 + 0], 0.f);
            v.y = fmaxf(v.y + b1[kk * 4 + 1], 0.f);
            v.z = fmaxf(v.z + b1[kk * 4 + 2], 0.f);
            v.w = fmaxf(v.w + b1[kk * 4 + 3], 0.f);
        }
        *(float4*)&hs[r][kk * 4] = v;
    }
    __syncthreads();
    int col = tid % OUT_DIM;
    int rg  = (tid / OUT_DIM) * 8;            // 8 groups x 8 rows = 64 rows
    float acc[8] = {};
    for (int k = 0; k < HID; k += 4) {
        float w0 = Ws[k + 0][col], w1 = Ws[k + 1][col];
        float w2 = Ws[k + 2][col], w3 = Ws[k + 3][col];
#pragma unroll
        for (int r = 0; r < 8; ++r) {
            float4 hv = *(float4*)&hs[rg + r][k];
            acc[r] = fmaf(hv.x, w0, acc[r]);
            acc[r] = fmaf(hv.y, w1, acc[r]);
            acc[r] = fmaf(hv.z, w2, acc[r]);
            acc[r] = fmaf(hv.w, w3, acc[r]);
        }
    }
#pragma unroll
    for (int r = 0; r < 8; ++r) {
        int gr = base + rg + r;
        if (gr < n) hw2[(size_t)gr * OUT_DIM + col] = __float2half(acc[r]);
    }
}

// ---------------- gather2 + finalize; 4x unrolled ----------------
__global__ void gather2_fin(const __half* __restrict__ hw2, const float* __restrict__ dinv,
                            const int* __restrict__ off, const int* __restrict__ sorted,
                            const float* __restrict__ b2, const float* __restrict__ P,
                            const float* __restrict__ Kv, const float* __restrict__ U,
                            float* __restrict__ out, int n) {
    int wid  = blockIdx.x * (blockDim.x >> 6) + (threadIdx.x >> 6);
    int lane = threadIdx.x & 63;
    if (wid >= n) return;
    float dd = dinv[wid];
    int cl = (lane < OUT_DIM) ? lane : 0;  // clamp so idle lanes load safely
    float acc = dd * dd * __half2float(hw2[(size_t)wid * OUT_DIM + cl]);
    int j = off[wid], en = off[wid + 1];
    for (; j + 4 <= en; j += 4) {
        int s0 = sorted[j + 0], s1 = sorted[j + 1];
        int s2 = sorted[j + 2], s3 = sorted[j + 3];
        float w0 = dinv[s0], w1 = dinv[s1], w2 = dinv[s2], w3 = dinv[s3];
        float v0 = __half2float(hw2[(size_t)s0 * OUT_DIM + cl]);
        float v1 = __half2float(hw2[(size_t)s1 * OUT_DIM + cl]);
        float v2 = __half2float(hw2[(size_t)s2 * OUT_DIM + cl]);
        float v3 = __half2float(hw2[(size_t)s3 * OUT_DIM + cl]);
        acc = fmaf(dd * w0, v0, acc);
        acc = fmaf(dd * w1, v1, acc);
        acc = fmaf(dd * w2, v2, acc);
        acc = fmaf(dd * w3, v3, acc);
    }
    for (; j < en; ++j) {
        int s = sorted[j];
        acc = fmaf(dd * dinv[s], __half2float(hw2[(size_t)s * OUT_DIM + cl]), acc);
    }
    float v = 0.f, y = -INFINITY;
    if (lane < OUT_DIM) {
        v = fmaxf(acc + b2[lane] + P[lane] * Kv[lane] * U[lane], 0.f);
        y = v;
    }
    float m = y;
#pragma unroll
    for (int o = 32; o; o >>= 1) m = fmaxf(m, __shfl_xor(m, o));
    float ex = (lane < OUT_DIM) ? __expf(v - m) : 0.f;
    float s2 = ex;
#pragma unroll
    for (int o = 32; o; o >>= 1) s2 += __shfl_xor(s2, o);
    float lse = m + __logf(s2);
    if (lane < OUT_DIM) out[(size_t)wid * OUT_DIM + lane] = v - lse;
}

extern "C" void kernel_launch(void* const* d_in, const int* in_sizes, int n_in,
                              void* d_out, int out_size, void* d_ws, size_t ws_size,
                              hipStream_t stream) {
    const float* x  = (const float*)d_in[0];
    const int*   ei = (const int*)d_in[1];
    const float* W1 = (const float*)d_in[2];
    const float* b1 = (const float*)d_in[3];
    const float* W2 = (const float*)d_in[4];
    const float* b2 = (const float*)d_in[5];
    const float* P  = (const float*)d_in[6];
    const float* K  = (const float*)d_in[7];
    const float* U  = (const float*)d_in[8];
    float* out = (float*)d_out;

    int n = in_sizes[0] / IN_DIM;   // 100000
    int e = in_sizes[1] / 2;        // 1600000
    const int* src = ei;
    const int* dst = ei + e;

    // workspace layout:
    // cnt[n] | dinv[n] | off[n+1] | cursor[n] | bsum[1024] | sorted[e]
    //   | hw1 fp16 [n*64] | agg1 f32 [n*64]
    int*    cnt    = (int*)d_ws;
    float*  dinv   = (float*)(cnt + n);
    int*    off    = (int*)(dinv + n);
    int*    cursor = off + (n + 1);
    int*    bsum   = cursor + n;
    int*    sorted = bsum + 1024;
    __half* hw1    = (__half*)(sorted + e);
    float*  agg1   = (float*)(hw1 + (size_t)n * HID);
    __half* hw2    = hw1;   // reuse hw1 slot (n*OUT_DIM*2B < n*HID*2B)

    int nb = (n + 1023) / 1024;  // 98

    hipMemsetAsync(cnt, 0, (size_t)n * sizeof(int), stream);
    count_k<<<(e + 255) / 256, 256, 0, stream>>>(dst, e, cnt);
    dinv_k<<<(n + 255) / 256, 256, 0, stream>>>(cnt, dinv, n);
    scan_local<<<nb, 256, 0, stream>>>(cnt, n, off, bsum);
    scan_bsum<<<1, 1024, 0, stream>>>(bsum, nb, n, off);
    scan_add<<<(n + 255) / 256, 256, 0, stream>>>(off, bsum, n, cursor);
    bin_k<<<(e + 255) / 256, 256, 0, stream>>>(src, dst, e, cursor, sorted);

    gemm1<<<(n + 31) / 32, 256, 0, stream>>>(x, W1, hw1, n);
    gather1<<<(n + 3) / 4, 256, 0, stream>>>(hw1, dinv, off, sorted, agg1, n);
    gemm2<<<(n + 63) / 64, 320, 0, stream>>>(agg1, W2, b1, hw2, n);
    gather2_fin<<<(n + 3) / 4, 256, 0, stream>>>(hw2, dinv, off, sorted,
                                                 b2, P, K, U, out, n);
}

// Round 6
// 498.560 us; speedup vs baseline: 1.3097x; 1.3097x over previous
//
#include <hip/hip_runtime.h>
#include <hip/hip_bf16.h>
#include <hip/hip_fp16.h>

#define IN_DIM 128
#define HID    64
#define OUT_DIM 40

// ---------------- degree count ----------------
__global__ void count_k(const int* __restrict__ dst, int e, int* __restrict__ cnt) {
    int i = blockIdx.x * blockDim.x + threadIdx.x;
    if (i < e) atomicAdd(&cnt[dst[i]], 1);
}

__global__ void dinv_k(const int* __restrict__ cnt, float* __restrict__ dinv, int n) {
    int i = blockIdx.x * blockDim.x + threadIdx.x;
    if (i < n) dinv[i] = rsqrtf((float)cnt[i] + 1.0f);
}

// ---------------- hierarchical exclusive scan ----------------
__global__ void scan_local(const int* __restrict__ cnt, int n,
                           int* __restrict__ off, int* __restrict__ bsum) {
    __shared__ int tmp[256];
    int t = threadIdx.x;
    int i0 = blockIdx.x * 1024 + t * 4;
    int c0 = (i0 + 0 < n) ? cnt[i0 + 0] : 0;
    int c1 = (i0 + 1 < n) ? cnt[i0 + 1] : 0;
    int c2 = (i0 + 2 < n) ? cnt[i0 + 2] : 0;
    int c3 = (i0 + 3 < n) ? cnt[i0 + 3] : 0;
    int s = c0 + c1 + c2 + c3;
    tmp[t] = s;
    __syncthreads();
    for (int ofs = 1; ofs < 256; ofs <<= 1) {
        int add = (t >= ofs) ? tmp[t - ofs] : 0;
        __syncthreads();
        tmp[t] += add;
        __syncthreads();
    }
    int run = tmp[t] - s;
    if (i0 + 0 < n) off[i0 + 0] = run; run += c0;
    if (i0 + 1 < n) off[i0 + 1] = run; run += c1;
    if (i0 + 2 < n) off[i0 + 2] = run; run += c2;
    if (i0 + 3 < n) off[i0 + 3] = run;
    if (t == 255) bsum[blockIdx.x] = tmp[255];
}

__global__ void scan_bsum(int* __restrict__ bsum, int nb, int n, int* __restrict__ off) {
    __shared__ int tmp[1024];
    int t = threadIdx.x;
    int v = (t < nb) ? bsum[t] : 0;
    tmp[t] = v;
    __syncthreads();
    for (int ofs = 1; ofs < 1024; ofs <<= 1) {
        int add = (t >= ofs) ? tmp[t - ofs] : 0;
        __syncthreads();
        tmp[t] += add;
        __syncthreads();
    }
    if (t < nb) bsum[t] = tmp[t] - v;
    if (t == 1023) off[n] = tmp[1023];
}

__global__ void scan_add(int* __restrict__ off, const int* __restrict__ bsum,
                         int n, int* __restrict__ cursor) {
    int i = blockIdx.x * blockDim.x + threadIdx.x;
    if (i < n) {
        int v = off[i] + bsum[i >> 10];
        off[i] = v;
        cursor[i] = v;
    }
}

__global__ void bin_k(const int* __restrict__ src, const int* __restrict__ dst, int e,
                      int* __restrict__ cursor, int* __restrict__ sorted) {
    int i = blockIdx.x * blockDim.x + threadIdx.x;
    if (i < e) {
        int d = dst[i];
        int pos = atomicAdd(&cursor[d], 1);
        sorted[pos] = src[i];
    }
}

// ---------------- GEMM1: hw1 = fp16(x @ W1), register-blocked ----------------
// 256 threads, tile 32 rows x 64 cols; thread = (col, rowgroup of 8)
__global__ __launch_bounds__(256) void gemm1(const float* __restrict__ x,
                                             const float* __restrict__ W1,
                                             __half* __restrict__ hw1, int n) {
    __shared__ float Ws[IN_DIM][HID];    // 32 KB, [k][col]
    __shared__ float xs[32][IN_DIM];     // 16 KB, [r][k]
    int tid = threadIdx.x;
    // stage W1 (coalesced float4)
    for (int i = tid * 4; i < IN_DIM * HID; i += 256 * 4)
        *(float4*)&Ws[0][i] = *(const float4*)&W1[i];
    // stage x tile (coalesced float4)
    int base = blockIdx.x * 32;
    for (int i = tid; i < 32 * IN_DIM / 4; i += 256) {
        int r = i >> 5, kk = i & 31;          // IN_DIM/4 = 32
        int gr = base + r;
        float4 v = {0.f, 0.f, 0.f, 0.f};
        if (gr < n) v = *(const float4*)&x[(size_t)gr * IN_DIM + kk * 4];
        *(float4*)&xs[r][kk * 4] = v;
    }
    __syncthreads();
    int col = tid & 63;
    int rg  = (tid >> 6) * 8;                 // 4 waves x 8 rows = 32 rows
    float acc[8] = {};
    for (int k = 0; k < IN_DIM; k += 4) {
        float w0 = Ws[k + 0][col], w1 = Ws[k + 1][col];
        float w2 = Ws[k + 2][col], w3 = Ws[k + 3][col];
#pragma unroll
        for (int r = 0; r < 8; ++r) {
            float4 xv = *(float4*)&xs[rg + r][k];   // wave-uniform broadcast
            acc[r] = fmaf(xv.x, w0, acc[r]);
            acc[r] = fmaf(xv.y, w1, acc[r]);
            acc[r] = fmaf(xv.z, w2, acc[r]);
            acc[r] = fmaf(xv.w, w3, acc[r]);
        }
    }
#pragma unroll
    for (int r = 0; r < 8; ++r) {
        int gr = base + rg + r;
        if (gr < n) hw1[(size_t)gr * HID + col] = __float2half(acc[r]);
    }
}

// ---------------- gather1: agg[d] = dinv^2*hw1[d] + sum norm*hw1[src] ----------
__global__ void gather1(const __half* __restrict__ hw1, const float* __restrict__ dinv,
                        const int* __restrict__ off, const int* __restrict__ sorted,
                        float* __restrict__ agg, int n) {
    int wid  = blockIdx.x * (blockDim.x >> 6) + (threadIdx.x >> 6);
    int lane = threadIdx.x & 63;
    if (wid >= n) return;
    float dd = dinv[wid];
    float acc = dd * dd * __half2float(hw1[(size_t)wid * HID + lane]);
    int j = off[wid], en = off[wid + 1];
    for (; j + 4 <= en; j += 4) {
        int s0 = sorted[j + 0], s1 = sorted[j + 1];
        int s2 = sorted[j + 2], s3 = sorted[j + 3];
        float w0 = dinv[s0], w1 = dinv[s1], w2 = dinv[s2], w3 = dinv[s3];
        float v0 = __half2float(hw1[(size_t)s0 * HID + lane]);
        float v1 = __half2float(hw1[(size_t)s1 * HID + lane]);
        float v2 = __half2float(hw1[(size_t)s2 * HID + lane]);
        float v3 = __half2float(hw1[(size_t)s3 * HID + lane]);
        acc = fmaf(dd * w0, v0, acc);
        acc = fmaf(dd * w1, v1, acc);
        acc = fmaf(dd * w2, v2, acc);
        acc = fmaf(dd * w3, v3, acc);
    }
    for (; j < en; ++j) {
        int s = sorted[j];
        acc = fmaf(dd * dinv[s], __half2float(hw1[(size_t)s * HID + lane]), acc);
    }
    agg[(size_t)wid * HID + lane] = acc;
}

// ---------------- GEMM2: hw2 = fp16(relu(h + b1) @ W2) ----------------
// EXACT mirror of gemm1's proven structure: 256 threads, 32-row tile,
// col = tid&63 with W2 zero-padded to 64 columns; store masked to col<40.
__global__ __launch_bounds__(256) void gemm2(const float* __restrict__ h,
                                             const float* __restrict__ W2,
                                             const float* __restrict__ b1,
                                             __half* __restrict__ hw2, int n) {
    __shared__ float Ws[HID][64];        // 16 KB, [k][col], cols 40..63 = 0
    __shared__ float hs[32][HID];        // 8 KB, [r][k]
    int tid = threadIdx.x;
    // stage W2 zero-padded
    for (int i = tid; i < HID * 64; i += 256) {
        int k = i >> 6, c = i & 63;
        Ws[k][c] = (c < OUT_DIM) ? W2[k * OUT_DIM + c] : 0.f;
    }
    // stage h tile with bias+relu (coalesced float4)
    int base = blockIdx.x * 32;
    for (int i = tid; i < 32 * HID / 4; i += 256) {
        int r = i >> 4, kk = i & 15;          // HID/4 = 16
        int gr = base + r;
        float4 v = {0.f, 0.f, 0.f, 0.f};
        if (gr < n) {
            v = *(const float4*)&h[(size_t)gr * HID + kk * 4];
            v.x = fmaxf(v.x + b1[kk * 4 + 0], 0.f);
            v.y = fmaxf(v.y + b1[kk * 4 + 1], 0.f);
            v.z = fmaxf(v.z + b1[kk * 4 + 2], 0.f);
            v.w = fmaxf(v.w + b1[kk * 4 + 3], 0.f);
        }
        *(float4*)&hs[r][kk * 4] = v;
    }
    __syncthreads();
    int col = tid & 63;
    int rg  = (tid >> 6) * 8;                 // 4 waves x 8 rows = 32 rows
    float acc[8] = {};
    for (int k = 0; k < HID; k += 4) {
        float w0 = Ws[k + 0][col], w1 = Ws[k + 1][col];
        float w2 = Ws[k + 2][col], w3 = Ws[k + 3][col];
#pragma unroll
        for (int r = 0; r < 8; ++r) {
            float4 hv = *(float4*)&hs[rg + r][k];
            acc[r] = fmaf(hv.x, w0, acc[r]);
            acc[r] = fmaf(hv.y, w1, acc[r]);
            acc[r] = fmaf(hv.z, w2, acc[r]);
            acc[r] = fmaf(hv.w, w3, acc[r]);
        }
    }
    if (col < OUT_DIM) {
#pragma unroll
        for (int r = 0; r < 8; ++r) {
            int gr = base + rg + r;
            if (gr < n) hw2[(size_t)gr * OUT_DIM + col] = __float2half(acc[r]);
        }
    }
}

// ---------------- gather2 + finalize; 4x unrolled ----------------
__global__ void gather2_fin(const __half* __restrict__ hw2, const float* __restrict__ dinv,
                            const int* __restrict__ off, const int* __restrict__ sorted,
                            const float* __restrict__ b2, const float* __restrict__ P,
                            const float* __restrict__ Kv, const float* __restrict__ U,
                            float* __restrict__ out, int n) {
    int wid  = blockIdx.x * (blockDim.x >> 6) + (threadIdx.x >> 6);
    int lane = threadIdx.x & 63;
    if (wid >= n) return;
    float dd = dinv[wid];
    int cl = (lane < OUT_DIM) ? lane : 0;  // clamp so idle lanes load safely
    float acc = dd * dd * __half2float(hw2[(size_t)wid * OUT_DIM + cl]);
    int j = off[wid], en = off[wid + 1];
    for (; j + 4 <= en; j += 4) {
        int s0 = sorted[j + 0], s1 = sorted[j + 1];
        int s2 = sorted[j + 2], s3 = sorted[j + 3];
        float w0 = dinv[s0], w1 = dinv[s1], w2 = dinv[s2], w3 = dinv[s3];
        float v0 = __half2float(hw2[(size_t)s0 * OUT_DIM + cl]);
        float v1 = __half2float(hw2[(size_t)s1 * OUT_DIM + cl]);
        float v2 = __half2float(hw2[(size_t)s2 * OUT_DIM + cl]);
        float v3 = __half2float(hw2[(size_t)s3 * OUT_DIM + cl]);
        acc = fmaf(dd * w0, v0, acc);
        acc = fmaf(dd * w1, v1, acc);
        acc = fmaf(dd * w2, v2, acc);
        acc = fmaf(dd * w3, v3, acc);
    }
    for (; j < en; ++j) {
        int s = sorted[j];
        acc = fmaf(dd * dinv[s], __half2float(hw2[(size_t)s * OUT_DIM + cl]), acc);
    }
    float v = 0.f, y = -INFINITY;
    if (lane < OUT_DIM) {
        v = fmaxf(acc + b2[lane] + P[lane] * Kv[lane] * U[lane], 0.f);
        y = v;
    }
    float m = y;
#pragma unroll
    for (int o = 32; o; o >>= 1) m = fmaxf(m, __shfl_xor(m, o));
    float ex = (lane < OUT_DIM) ? __expf(v - m) : 0.f;
    float s2 = ex;
#pragma unroll
    for (int o = 32; o; o >>= 1) s2 += __shfl_xor(s2, o);
    float lse = m + __logf(s2);
    if (lane < OUT_DIM) out[(size_t)wid * OUT_DIM + lane] = v - lse;
}

extern "C" void kernel_launch(void* const* d_in, const int* in_sizes, int n_in,
                              void* d_out, int out_size, void* d_ws, size_t ws_size,
                              hipStream_t stream) {
    const float* x  = (const float*)d_in[0];
    const int*   ei = (const int*)d_in[1];
    const float* W1 = (const float*)d_in[2];
    const float* b1 = (const float*)d_in[3];
    const float* W2 = (const float*)d_in[4];
    const float* b2 = (const float*)d_in[5];
    const float* P  = (const float*)d_in[6];
    const float* K  = (const float*)d_in[7];
    const float* U  = (const float*)d_in[8];
    float* out = (float*)d_out;

    int n = in_sizes[0] / IN_DIM;   // 100000
    int e = in_sizes[1] / 2;        // 1600000
    const int* src = ei;
    const int* dst = ei + e;

    // workspace layout:
    // cnt[n] | dinv[n] | off[n+1] | cursor[n] | bsum[1024] | sorted[e]
    //   | hw1 fp16 [n*64] | agg1 f32 [n*64]
    int*    cnt    = (int*)d_ws;
    float*  dinv   = (float*)(cnt + n);
    int*    off    = (int*)(dinv + n);
    int*    cursor = off + (n + 1);
    int*    bsum   = cursor + n;
    int*    sorted = bsum + 1024;
    __half* hw1    = (__half*)(sorted + e);
    float*  agg1   = (float*)(hw1 + (size_t)n * HID);
    __half* hw2    = hw1;   // reuse hw1 slot (n*OUT_DIM*2B < n*HID*2B)

    int nb = (n + 1023) / 1024;  // 98

    hipMemsetAsync(cnt, 0, (size_t)n * sizeof(int), stream);
    count_k<<<(e + 255) / 256, 256, 0, stream>>>(dst, e, cnt);
    dinv_k<<<(n + 255) / 256, 256, 0, stream>>>(cnt, dinv, n);
    scan_local<<<nb, 256, 0, stream>>>(cnt, n, off, bsum);
    scan_bsum<<<1, 1024, 0, stream>>>(bsum, nb, n, off);
    scan_add<<<(n + 255) / 256, 256, 0, stream>>>(off, bsum, n, cursor);
    bin_k<<<(e + 255) / 256, 256, 0, stream>>>(src, dst, e, cursor, sorted);

    gemm1<<<(n + 31) / 32, 256, 0, stream>>>(x, W1, hw1, n);
    gather1<<<(n + 3) / 4, 256, 0, stream>>>(hw1, dinv, off, sorted, agg1, n);
    gemm2<<<(n + 31) / 32, 256, 0, stream>>>(agg1, W2, b1, hw2, n);
    gather2_fin<<<(n + 3) / 4, 256, 0, stream>>>(hw2, dinv, off, sorted,
                                                 b2, P, K, U, out, n);
}

// Round 7
// 425.707 us; speedup vs baseline: 1.5338x; 1.1711x over previous
//
#include <hip/hip_runtime.h>
#include <hip/hip_bf16.h>
#include <hip/hip_fp16.h>

#define IN_DIM 128
#define HID    64
#define OUT_DIM 40

// ---------------- degree count ----------------
__global__ void count_k(const int* __restrict__ dst, int e, int* __restrict__ cnt) {
    int i = blockIdx.x * blockDim.x + threadIdx.x;
    if (i < e) atomicAdd(&cnt[dst[i]], 1);
}

__global__ void dinv_k(const int* __restrict__ cnt, float* __restrict__ dinv, int n) {
    int i = blockIdx.x * blockDim.x + threadIdx.x;
    if (i < n) dinv[i] = rsqrtf((float)cnt[i] + 1.0f);
}

// ---------------- hierarchical exclusive scan ----------------
__global__ void scan_local(const int* __restrict__ cnt, int n,
                           int* __restrict__ off, int* __restrict__ bsum) {
    __shared__ int tmp[256];
    int t = threadIdx.x;
    int i0 = blockIdx.x * 1024 + t * 4;
    int c0 = (i0 + 0 < n) ? cnt[i0 + 0] : 0;
    int c1 = (i0 + 1 < n) ? cnt[i0 + 1] : 0;
    int c2 = (i0 + 2 < n) ? cnt[i0 + 2] : 0;
    int c3 = (i0 + 3 < n) ? cnt[i0 + 3] : 0;
    int s = c0 + c1 + c2 + c3;
    tmp[t] = s;
    __syncthreads();
    for (int ofs = 1; ofs < 256; ofs <<= 1) {
        int add = (t >= ofs) ? tmp[t - ofs] : 0;
        __syncthreads();
        tmp[t] += add;
        __syncthreads();
    }
    int run = tmp[t] - s;
    if (i0 + 0 < n) off[i0 + 0] = run; run += c0;
    if (i0 + 1 < n) off[i0 + 1] = run; run += c1;
    if (i0 + 2 < n) off[i0 + 2] = run; run += c2;
    if (i0 + 3 < n) off[i0 + 3] = run;
    if (t == 255) bsum[blockIdx.x] = tmp[255];
}

__global__ void scan_bsum(int* __restrict__ bsum, int nb, int n, int* __restrict__ off) {
    __shared__ int tmp[1024];
    int t = threadIdx.x;
    int v = (t < nb) ? bsum[t] : 0;
    tmp[t] = v;
    __syncthreads();
    for (int ofs = 1; ofs < 1024; ofs <<= 1) {
        int add = (t >= ofs) ? tmp[t - ofs] : 0;
        __syncthreads();
        tmp[t] += add;
        __syncthreads();
    }
    if (t < nb) bsum[t] = tmp[t] - v;
    if (t == 1023) off[n] = tmp[1023];
}

__global__ void scan_add(int* __restrict__ off, const int* __restrict__ bsum,
                         int n, int* __restrict__ cursor) {
    int i = blockIdx.x * blockDim.x + threadIdx.x;
    if (i < n) {
        int v = off[i] + bsum[i >> 10];
        off[i] = v;
        cursor[i] = v;
    }
}

__global__ void bin_k(const int* __restrict__ src, const int* __restrict__ dst, int e,
                      int* __restrict__ cursor, int* __restrict__ sorted) {
    int i = blockIdx.x * blockDim.x + threadIdx.x;
    if (i < e) {
        int d = dst[i];
        int pos = atomicAdd(&cursor[d], 1);
        sorted[pos] = src[i];
    }
}

// ---------------- GEMM1: hw1 = fp16(x @ W1), register-blocked ----------------
// 256 threads, tile 32 rows x 64 cols; thread = (col, rowgroup of 8)
__global__ __launch_bounds__(256) void gemm1(const float* __restrict__ x,
                                             const float* __restrict__ W1,
                                             __half* __restrict__ hw1, int n) {
    __shared__ float Ws[IN_DIM][HID];    // 32 KB, [k][col]
    __shared__ float xs[32][IN_DIM];     // 16 KB, [r][k]
    int tid = threadIdx.x;
    // stage W1 (coalesced float4)
    for (int i = tid * 4; i < IN_DIM * HID; i += 256 * 4)
        *(float4*)&Ws[0][i] = *(const float4*)&W1[i];
    // stage x tile (coalesced float4)
    int base = blockIdx.x * 32;
    for (int i = tid; i < 32 * IN_DIM / 4; i += 256) {
        int r = i >> 5, kk = i & 31;          // IN_DIM/4 = 32
        int gr = base + r;
        float4 v = {0.f, 0.f, 0.f, 0.f};
        if (gr < n) v = *(const float4*)&x[(size_t)gr * IN_DIM + kk * 4];
        *(float4*)&xs[r][kk * 4] = v;
    }
    __syncthreads();
    int col = tid & 63;
    int rg  = (tid >> 6) * 8;                 // 4 waves x 8 rows = 32 rows
    float acc[8] = {};
#pragma unroll 2
    for (int k = 0; k < IN_DIM; k += 4) {
        float w0 = Ws[k + 0][col], w1 = Ws[k + 1][col];
        float w2 = Ws[k + 2][col], w3 = Ws[k + 3][col];
#pragma unroll
        for (int r = 0; r < 8; ++r) {
            float4 xv = *(float4*)&xs[rg + r][k];   // wave-uniform broadcast
            acc[r] = fmaf(xv.x, w0, acc[r]);
            acc[r] = fmaf(xv.y, w1, acc[r]);
            acc[r] = fmaf(xv.z, w2, acc[r]);
            acc[r] = fmaf(xv.w, w3, acc[r]);
        }
    }
#pragma unroll
    for (int r = 0; r < 8; ++r) {
        int gr = base + rg + r;
        if (gr < n) hw1[(size_t)gr * HID + col] = __float2half(acc[r]);
    }
}

// ---------------- gather1: agg[d] = dinv^2*hw1[d] + sum norm*hw1[src] ----------
__global__ void gather1(const __half* __restrict__ hw1, const float* __restrict__ dinv,
                        const int* __restrict__ off, const int* __restrict__ sorted,
                        float* __restrict__ agg, int n) {
    int wid  = blockIdx.x * (blockDim.x >> 6) + (threadIdx.x >> 6);
    int lane = threadIdx.x & 63;
    if (wid >= n) return;
    float dd = dinv[wid];
    float acc = dd * dd * __half2float(hw1[(size_t)wid * HID + lane]);
    int j = off[wid], en = off[wid + 1];
    for (; j + 4 <= en; j += 4) {
        int s0 = sorted[j + 0], s1 = sorted[j + 1];
        int s2 = sorted[j + 2], s3 = sorted[j + 3];
        float w0 = dinv[s0], w1 = dinv[s1], w2 = dinv[s2], w3 = dinv[s3];
        float v0 = __half2float(hw1[(size_t)s0 * HID + lane]);
        float v1 = __half2float(hw1[(size_t)s1 * HID + lane]);
        float v2 = __half2float(hw1[(size_t)s2 * HID + lane]);
        float v3 = __half2float(hw1[(size_t)s3 * HID + lane]);
        acc = fmaf(dd * w0, v0, acc);
        acc = fmaf(dd * w1, v1, acc);
        acc = fmaf(dd * w2, v2, acc);
        acc = fmaf(dd * w3, v3, acc);
    }
    for (; j < en; ++j) {
        int s = sorted[j];
        acc = fmaf(dd * dinv[s], __half2float(hw1[(size_t)s * HID + lane]), acc);
    }
    agg[(size_t)wid * HID + lane] = acc;
}

// ---------------- GEMM2: hw2 = fp16(relu(h + b1) @ W2) ----------------
// gemm1-mirror structure; k-loop unroll PINNED to 2 to avoid the full-unroll
// register blowup (R5: VGPR=256, 117 MB scratch writes, 130 us).
__global__ __launch_bounds__(256) void gemm2(const float* __restrict__ h,
                                             const float* __restrict__ W2,
                                             const float* __restrict__ b1,
                                             __half* __restrict__ hw2, int n) {
    __shared__ float Ws[HID][64];        // 16 KB, [k][col], cols 40..63 = 0
    __shared__ float hs[32][HID];        // 8 KB, [r][k]
    int tid = threadIdx.x;
    // stage W2 zero-padded
    for (int i = tid; i < HID * 64; i += 256) {
        int k = i >> 6, c = i & 63;
        Ws[k][c] = (c < OUT_DIM) ? W2[k * OUT_DIM + c] : 0.f;
    }
    // stage h tile with bias+relu (coalesced float4)
    int base = blockIdx.x * 32;
    for (int i = tid; i < 32 * HID / 4; i += 256) {
        int r = i >> 4, kk = i & 15;          // HID/4 = 16
        int gr = base + r;
        float4 v = {0.f, 0.f, 0.f, 0.f};
        if (gr < n) {
            v = *(const float4*)&h[(size_t)gr * HID + kk * 4];
            v.x = fmaxf(v.x + b1[kk * 4 + 0], 0.f);
            v.y = fmaxf(v.y + b1[kk * 4 + 1], 0.f);
            v.z = fmaxf(v.z + b1[kk * 4 + 2], 0.f);
            v.w = fmaxf(v.w + b1[kk * 4 + 3], 0.f);
        }
        *(float4*)&hs[r][kk * 4] = v;
    }
    __syncthreads();
    int col = tid & 63;
    int rg  = (tid >> 6) * 8;                 // 4 waves x 8 rows = 32 rows
    float acc[8] = {};
#pragma unroll 2
    for (int k = 0; k < HID; k += 4) {
        float w0 = Ws[k + 0][col], w1 = Ws[k + 1][col];
        float w2 = Ws[k + 2][col], w3 = Ws[k + 3][col];
#pragma unroll
        for (int r = 0; r < 8; ++r) {
            float4 hv = *(float4*)&hs[rg + r][k];
            acc[r] = fmaf(hv.x, w0, acc[r]);
            acc[r] = fmaf(hv.y, w1, acc[r]);
            acc[r] = fmaf(hv.z, w2, acc[r]);
            acc[r] = fmaf(hv.w, w3, acc[r]);
        }
    }
    if (col < OUT_DIM) {
#pragma unroll
        for (int r = 0; r < 8; ++r) {
            int gr = base + rg + r;
            if (gr < n) hw2[(size_t)gr * OUT_DIM + col] = __float2half(acc[r]);
        }
    }
}

// ---------------- gather2 + finalize; 4x unrolled ----------------
__global__ void gather2_fin(const __half* __restrict__ hw2, const float* __restrict__ dinv,
                            const int* __restrict__ off, const int* __restrict__ sorted,
                            const float* __restrict__ b2, const float* __restrict__ P,
                            const float* __restrict__ Kv, const float* __restrict__ U,
                            float* __restrict__ out, int n) {
    int wid  = blockIdx.x * (blockDim.x >> 6) + (threadIdx.x >> 6);
    int lane = threadIdx.x & 63;
    if (wid >= n) return;
    float dd = dinv[wid];
    int cl = (lane < OUT_DIM) ? lane : 0;  // clamp so idle lanes load safely
    float acc = dd * dd * __half2float(hw2[(size_t)wid * OUT_DIM + cl]);
    int j = off[wid], en = off[wid + 1];
    for (; j + 4 <= en; j += 4) {
        int s0 = sorted[j + 0], s1 = sorted[j + 1];
        int s2 = sorted[j + 2], s3 = sorted[j + 3];
        float w0 = dinv[s0], w1 = dinv[s1], w2 = dinv[s2], w3 = dinv[s3];
        float v0 = __half2float(hw2[(size_t)s0 * OUT_DIM + cl]);
        float v1 = __half2float(hw2[(size_t)s1 * OUT_DIM + cl]);
        float v2 = __half2float(hw2[(size_t)s2 * OUT_DIM + cl]);
        float v3 = __half2float(hw2[(size_t)s3 * OUT_DIM + cl]);
        acc = fmaf(dd * w0, v0, acc);
        acc = fmaf(dd * w1, v1, acc);
        acc = fmaf(dd * w2, v2, acc);
        acc = fmaf(dd * w3, v3, acc);
    }
    for (; j < en; ++j) {
        int s = sorted[j];
        acc = fmaf(dd * dinv[s], __half2float(hw2[(size_t)s * OUT_DIM + cl]), acc);
    }
    float v = 0.f, y = -INFINITY;
    if (lane < OUT_DIM) {
        v = fmaxf(acc + b2[lane] + P[lane] * Kv[lane] * U[lane], 0.f);
        y = v;
    }
    float m = y;
#pragma unroll
    for (int o = 32; o; o >>= 1) m = fmaxf(m, __shfl_xor(m, o));
    float ex = (lane < OUT_DIM) ? __expf(v - m) : 0.f;
    float s2 = ex;
#pragma unroll
    for (int o = 32; o; o >>= 1) s2 += __shfl_xor(s2, o);
    float lse = m + __logf(s2);
    if (lane < OUT_DIM) out[(size_t)wid * OUT_DIM + lane] = v - lse;
}

extern "C" void kernel_launch(void* const* d_in, const int* in_sizes, int n_in,
                              void* d_out, int out_size, void* d_ws, size_t ws_size,
                              hipStream_t stream) {
    const float* x  = (const float*)d_in[0];
    const int*   ei = (const int*)d_in[1];
    const float* W1 = (const float*)d_in[2];
    const float* b1 = (const float*)d_in[3];
    const float* W2 = (const float*)d_in[4];
    const float* b2 = (const float*)d_in[5];
    const float* P  = (const float*)d_in[6];
    const float* K  = (const float*)d_in[7];
    const float* U  = (const float*)d_in[8];
    float* out = (float*)d_out;

    int n = in_sizes[0] / IN_DIM;   // 100000
    int e = in_sizes[1] / 2;        // 1600000
    const int* src = ei;
    const int* dst = ei + e;

    // workspace layout:
    // cnt[n] | dinv[n] | off[n+1] | cursor[n] | bsum[1024] | sorted[e]
    //   | hw1 fp16 [n*64] | agg1 f32 [n*64]
    int*    cnt    = (int*)d_ws;
    float*  dinv   = (float*)(cnt + n);
    int*    off    = (int*)(dinv + n);
    int*    cursor = off + (n + 1);
    int*    bsum   = cursor + n;
    int*    sorted = bsum + 1024;
    __half* hw1    = (__half*)(sorted + e);
    float*  agg1   = (float*)(hw1 + (size_t)n * HID);
    __half* hw2    = hw1;   // reuse hw1 slot (n*OUT_DIM*2B < n*HID*2B)

    int nb = (n + 1023) / 1024;  // 98

    hipMemsetAsync(cnt, 0, (size_t)n * sizeof(int), stream);
    count_k<<<(e + 255) / 256, 256, 0, stream>>>(dst, e, cnt);
    dinv_k<<<(n + 255) / 256, 256, 0, stream>>>(cnt, dinv, n);
    scan_local<<<nb, 256, 0, stream>>>(cnt, n, off, bsum);
    scan_bsum<<<1, 1024, 0, stream>>>(bsum, nb, n, off);
    scan_add<<<(n + 255) / 256, 256, 0, stream>>>(off, bsum, n, cursor);
    bin_k<<<(e + 255) / 256, 256, 0, stream>>>(src, dst, e, cursor, sorted);

    gemm1<<<(n + 31) / 32, 256, 0, stream>>>(x, W1, hw1, n);
    gather1<<<(n + 3) / 4, 256, 0, stream>>>(hw1, dinv, off, sorted, agg1, n);
    gemm2<<<(n + 31) / 32, 256, 0, stream>>>(agg1, W2, b1, hw2, n);
    gather2_fin<<<(n + 3) / 4, 256, 0, stream>>>(hw2, dinv, off, sorted,
                                                 b2, P, K, U, out, n);
}

// Round 8
// 336.805 us; speedup vs baseline: 1.9387x; 1.2640x over previous
//
#include <hip/hip_runtime.h>
#include <hip/hip_bf16.h>
#include <hip/hip_fp16.h>

#define IN_DIM 128
#define HID    64
#define OUT_DIM 40
#define GRP_SH 8                  // 256 nodes per coarse bucket
#define CB_TILE 4096              // edges per coarse_bin block

// ---------------- degree count ----------------
__global__ void count_k(const int* __restrict__ dst, int e, int* __restrict__ cnt) {
    int i = blockIdx.x * blockDim.x + threadIdx.x;
    if (i < e) atomicAdd(&cnt[dst[i]], 1);
}

__global__ void dinv_k(const int* __restrict__ cnt, float* __restrict__ dinv, int n) {
    int i = blockIdx.x * blockDim.x + threadIdx.x;
    if (i < n) dinv[i] = rsqrtf((float)cnt[i] + 1.0f);
}

// ---------------- hierarchical exclusive scan ----------------
__global__ void scan_local(const int* __restrict__ cnt, int n,
                           int* __restrict__ off, int* __restrict__ bsum) {
    __shared__ int tmp[256];
    int t = threadIdx.x;
    int i0 = blockIdx.x * 1024 + t * 4;
    int c0 = (i0 + 0 < n) ? cnt[i0 + 0] : 0;
    int c1 = (i0 + 1 < n) ? cnt[i0 + 1] : 0;
    int c2 = (i0 + 2 < n) ? cnt[i0 + 2] : 0;
    int c3 = (i0 + 3 < n) ? cnt[i0 + 3] : 0;
    int s = c0 + c1 + c2 + c3;
    tmp[t] = s;
    __syncthreads();
    for (int ofs = 1; ofs < 256; ofs <<= 1) {
        int add = (t >= ofs) ? tmp[t - ofs] : 0;
        __syncthreads();
        tmp[t] += add;
        __syncthreads();
    }
    int run = tmp[t] - s;
    if (i0 + 0 < n) off[i0 + 0] = run; run += c0;
    if (i0 + 1 < n) off[i0 + 1] = run; run += c1;
    if (i0 + 2 < n) off[i0 + 2] = run; run += c2;
    if (i0 + 3 < n) off[i0 + 3] = run;
    if (t == 255) bsum[blockIdx.x] = tmp[255];
}

__global__ void scan_bsum(int* __restrict__ bsum, int nb, int n, int* __restrict__ off) {
    __shared__ int tmp[1024];
    int t = threadIdx.x;
    int v = (t < nb) ? bsum[t] : 0;
    tmp[t] = v;
    __syncthreads();
    for (int ofs = 1; ofs < 1024; ofs <<= 1) {
        int add = (t >= ofs) ? tmp[t - ofs] : 0;
        __syncthreads();
        tmp[t] += add;
        __syncthreads();
    }
    if (t < nb) bsum[t] = tmp[t] - v;
    if (t == 1023) off[n] = tmp[1023];
}

__global__ void scan_add(int* __restrict__ off, const int* __restrict__ bsum,
                         int n, int* __restrict__ cursor) {
    int i = blockIdx.x * blockDim.x + threadIdx.x;
    if (i < n) {
        int v = off[i] + bsum[i >> 10];
        off[i] = v;
        cursor[i] = v;
    }
}

// ccur[b] = off[min(b*256, n)]  (coarse-bucket cursors)
__global__ void init_ccur(const int* __restrict__ off, int n, int nbuk,
                          int* __restrict__ ccur) {
    int b = blockIdx.x * blockDim.x + threadIdx.x;
    if (b < nbuk) {
        int node = b << GRP_SH;
        ccur[b] = off[node < n ? node : n];
    }
}

// ---------------- coarse bin: edges -> (src,dst) pairs grouped by dst>>8 ------
// Per block: stash 4096 edges in regs, LDS-count per bucket, reserve runs with
// one global atomic per (block,bucket), write pairs into contiguous runs.
__global__ __launch_bounds__(256) void coarse_bin(const int* __restrict__ src,
                                                  const int* __restrict__ dst, int e,
                                                  int nbuk, int* __restrict__ ccur,
                                                  int2* __restrict__ pairs) {
    __shared__ int lcnt[512];
    __shared__ int gbase[512];
    int t = threadIdx.x;
    for (int i = t; i < nbuk; i += 256) lcnt[i] = 0;
    __syncthreads();
    int base = blockIdx.x * CB_TILE;
    int s[16], d[16];
#pragma unroll
    for (int q = 0; q < 16; ++q) {
        int i = base + q * 256 + t;            // coalesced
        if (i < e) { s[q] = src[i]; d[q] = dst[i]; }
        else d[q] = -1;
    }
#pragma unroll
    for (int q = 0; q < 16; ++q)
        if (d[q] >= 0) atomicAdd(&lcnt[d[q] >> GRP_SH], 1);
    __syncthreads();
    for (int b = t; b < nbuk; b += 256) {
        int c = lcnt[b];
        gbase[b] = c ? atomicAdd(&ccur[b], c) : 0;
        lcnt[b] = 0;                            // reuse as local slot counter
    }
    __syncthreads();
#pragma unroll
    for (int q = 0; q < 16; ++q) {
        if (d[q] >= 0) {
            int b = d[q] >> GRP_SH;
            int slot = atomicAdd(&lcnt[b], 1);
            pairs[gbase[b] + slot] = make_int2(s[q], d[q]);
        }
    }
}

// ---------------- fine bin: block b exclusively scatters bucket b ------------
// All writes land in the bucket's ~17 KB CSR window -> L2-resident, lines
// fully dirtied -> writeback == window size (kills the 16x amplification).
__global__ __launch_bounds__(256) void fine_bin(const int2* __restrict__ pairs,
                                                const int* __restrict__ off, int n,
                                                int* __restrict__ cursor,
                                                int* __restrict__ sorted) {
    int b = blockIdx.x;
    int nlo = b << GRP_SH, nhi = (b + 1) << GRP_SH;
    int lo = off[nlo < n ? nlo : n];
    int hi = off[nhi < n ? nhi : n];
    for (int j = lo + threadIdx.x; j < hi; j += 256) {
        int2 p = pairs[j];
        int pos = atomicAdd(&cursor[p.y], 1);
        sorted[pos] = p.x;
    }
}

// ---------------- GEMM1: hw1 = fp16(x @ W1), register-blocked ----------------
__global__ __launch_bounds__(256) void gemm1(const float* __restrict__ x,
                                             const float* __restrict__ W1,
                                             __half* __restrict__ hw1, int n) {
    __shared__ float Ws[IN_DIM][HID];    // 32 KB, [k][col]
    __shared__ float xs[32][IN_DIM];     // 16 KB, [r][k]
    int tid = threadIdx.x;
    for (int i = tid * 4; i < IN_DIM * HID; i += 256 * 4)
        *(float4*)&Ws[0][i] = *(const float4*)&W1[i];
    int base = blockIdx.x * 32;
    for (int i = tid; i < 32 * IN_DIM / 4; i += 256) {
        int r = i >> 5, kk = i & 31;
        int gr = base + r;
        float4 v = {0.f, 0.f, 0.f, 0.f};
        if (gr < n) v = *(const float4*)&x[(size_t)gr * IN_DIM + kk * 4];
        *(float4*)&xs[r][kk * 4] = v;
    }
    __syncthreads();
    int col = tid & 63;
    int rg  = (tid >> 6) * 8;
    float acc[8] = {};
#pragma unroll 2
    for (int k = 0; k < IN_DIM; k += 4) {
        float w0 = Ws[k + 0][col], w1 = Ws[k + 1][col];
        float w2 = Ws[k + 2][col], w3 = Ws[k + 3][col];
#pragma unroll
        for (int r = 0; r < 8; ++r) {
            float4 xv = *(float4*)&xs[rg + r][k];
            acc[r] = fmaf(xv.x, w0, acc[r]);
            acc[r] = fmaf(xv.y, w1, acc[r]);
            acc[r] = fmaf(xv.z, w2, acc[r]);
            acc[r] = fmaf(xv.w, w3, acc[r]);
        }
    }
#pragma unroll
    for (int r = 0; r < 8; ++r) {
        int gr = base + rg + r;
        if (gr < n) hw1[(size_t)gr * HID + col] = __float2half(acc[r]);
    }
}

// ---------------- gather1: agg[d] = dinv^2*hw1[d] + sum norm*hw1[src] ----------
__global__ void gather1(const __half* __restrict__ hw1, const float* __restrict__ dinv,
                        const int* __restrict__ off, const int* __restrict__ sorted,
                        float* __restrict__ agg, int n) {
    int wid  = blockIdx.x * (blockDim.x >> 6) + (threadIdx.x >> 6);
    int lane = threadIdx.x & 63;
    if (wid >= n) return;
    float dd = dinv[wid];
    float acc = dd * dd * __half2float(hw1[(size_t)wid * HID + lane]);
    int j = off[wid], en = off[wid + 1];
    for (; j + 8 <= en; j += 8) {
        int ss[8]; float ww[8], vv[8];
#pragma unroll
        for (int q = 0; q < 8; ++q) ss[q] = sorted[j + q];
#pragma unroll
        for (int q = 0; q < 8; ++q) ww[q] = dinv[ss[q]];
#pragma unroll
        for (int q = 0; q < 8; ++q) vv[q] = __half2float(hw1[(size_t)ss[q] * HID + lane]);
#pragma unroll
        for (int q = 0; q < 8; ++q) acc = fmaf(dd * ww[q], vv[q], acc);
    }
    for (; j + 4 <= en; j += 4) {
        int s0 = sorted[j + 0], s1 = sorted[j + 1];
        int s2 = sorted[j + 2], s3 = sorted[j + 3];
        float w0 = dinv[s0], w1 = dinv[s1], w2 = dinv[s2], w3 = dinv[s3];
        float v0 = __half2float(hw1[(size_t)s0 * HID + lane]);
        float v1 = __half2float(hw1[(size_t)s1 * HID + lane]);
        float v2 = __half2float(hw1[(size_t)s2 * HID + lane]);
        float v3 = __half2float(hw1[(size_t)s3 * HID + lane]);
        acc = fmaf(dd * w0, v0, acc);
        acc = fmaf(dd * w1, v1, acc);
        acc = fmaf(dd * w2, v2, acc);
        acc = fmaf(dd * w3, v3, acc);
    }
    for (; j < en; ++j) {
        int s = sorted[j];
        acc = fmaf(dd * dinv[s], __half2float(hw1[(size_t)s * HID + lane]), acc);
    }
    agg[(size_t)wid * HID + lane] = acc;
}

// ---------------- GEMM2: hw2 = fp16(relu(h + b1) @ W2) ----------------
__global__ __launch_bounds__(256) void gemm2(const float* __restrict__ h,
                                             const float* __restrict__ W2,
                                             const float* __restrict__ b1,
                                             __half* __restrict__ hw2, int n) {
    __shared__ float Ws[HID][64];        // cols 40..63 = 0
    __shared__ float hs[32][HID];
    int tid = threadIdx.x;
    for (int i = tid; i < HID * 64; i += 256) {
        int k = i >> 6, c = i & 63;
        Ws[k][c] = (c < OUT_DIM) ? W2[k * OUT_DIM + c] : 0.f;
    }
    int base = blockIdx.x * 32;
    for (int i = tid; i < 32 * HID / 4; i += 256) {
        int r = i >> 4, kk = i & 15;
        int gr = base + r;
        float4 v = {0.f, 0.f, 0.f, 0.f};
        if (gr < n) {
            v = *(const float4*)&h[(size_t)gr * HID + kk * 4];
            v.x = fmaxf(v.x + b1[kk * 4 + 0], 0.f);
            v.y = fmaxf(v.y + b1[kk * 4 + 1], 0.f);
            v.z = fmaxf(v.z + b1[kk * 4 + 2], 0.f);
            v.w = fmaxf(v.w + b1[kk * 4 + 3], 0.f);
        }
        *(float4*)&hs[r][kk * 4] = v;
    }
    __syncthreads();
    int col = tid & 63;
    int rg  = (tid >> 6) * 8;
    float acc[8] = {};
#pragma unroll 2
    for (int k = 0; k < HID; k += 4) {
        float w0 = Ws[k + 0][col], w1 = Ws[k + 1][col];
        float w2 = Ws[k + 2][col], w3 = Ws[k + 3][col];
#pragma unroll
        for (int r = 0; r < 8; ++r) {
            float4 hv = *(float4*)&hs[rg + r][k];
            acc[r] = fmaf(hv.x, w0, acc[r]);
            acc[r] = fmaf(hv.y, w1, acc[r]);
            acc[r] = fmaf(hv.z, w2, acc[r]);
            acc[r] = fmaf(hv.w, w3, acc[r]);
        }
    }
    if (col < OUT_DIM) {
#pragma unroll
        for (int r = 0; r < 8; ++r) {
            int gr = base + rg + r;
            if (gr < n) hw2[(size_t)gr * OUT_DIM + col] = __float2half(acc[r]);
        }
    }
}

// ---------------- gather2 + finalize ----------------
__global__ void gather2_fin(const __half* __restrict__ hw2, const float* __restrict__ dinv,
                            const int* __restrict__ off, const int* __restrict__ sorted,
                            const float* __restrict__ b2, const float* __restrict__ P,
                            const float* __restrict__ Kv, const float* __restrict__ U,
                            float* __restrict__ out, int n) {
    int wid  = blockIdx.x * (blockDim.x >> 6) + (threadIdx.x >> 6);
    int lane = threadIdx.x & 63;
    if (wid >= n) return;
    float dd = dinv[wid];
    int cl = (lane < OUT_DIM) ? lane : 0;
    float acc = dd * dd * __half2float(hw2[(size_t)wid * OUT_DIM + cl]);
    int j = off[wid], en = off[wid + 1];
    for (; j + 8 <= en; j += 8) {
        int ss[8]; float ww[8], vv[8];
#pragma unroll
        for (int q = 0; q < 8; ++q) ss[q] = sorted[j + q];
#pragma unroll
        for (int q = 0; q < 8; ++q) ww[q] = dinv[ss[q]];
#pragma unroll
        for (int q = 0; q < 8; ++q) vv[q] = __half2float(hw2[(size_t)ss[q] * OUT_DIM + cl]);
#pragma unroll
        for (int q = 0; q < 8; ++q) acc = fmaf(dd * ww[q], vv[q], acc);
    }
    for (; j + 4 <= en; j += 4) {
        int s0 = sorted[j + 0], s1 = sorted[j + 1];
        int s2 = sorted[j + 2], s3 = sorted[j + 3];
        float w0 = dinv[s0], w1 = dinv[s1], w2 = dinv[s2], w3 = dinv[s3];
        float v0 = __half2float(hw2[(size_t)s0 * OUT_DIM + cl]);
        float v1 = __half2float(hw2[(size_t)s1 * OUT_DIM + cl]);
        float v2 = __half2float(hw2[(size_t)s2 * OUT_DIM + cl]);
        float v3 = __half2float(hw2[(size_t)s3 * OUT_DIM + cl]);
        acc = fmaf(dd * w0, v0, acc);
        acc = fmaf(dd * w1, v1, acc);
        acc = fmaf(dd * w2, v2, acc);
        acc = fmaf(dd * w3, v3, acc);
    }
    for (; j < en; ++j) {
        int s = sorted[j];
        acc = fmaf(dd * dinv[s], __half2float(hw2[(size_t)s * OUT_DIM + cl]), acc);
    }
    float v = 0.f, y = -INFINITY;
    if (lane < OUT_DIM) {
        v = fmaxf(acc + b2[lane] + P[lane] * Kv[lane] * U[lane], 0.f);
        y = v;
    }
    float m = y;
#pragma unroll
    for (int o = 32; o; o >>= 1) m = fmaxf(m, __shfl_xor(m, o));
    float ex = (lane < OUT_DIM) ? __expf(v - m) : 0.f;
    float s2 = ex;
#pragma unroll
    for (int o = 32; o; o >>= 1) s2 += __shfl_xor(s2, o);
    float lse = m + __logf(s2);
    if (lane < OUT_DIM) out[(size_t)wid * OUT_DIM + lane] = v - lse;
}

extern "C" void kernel_launch(void* const* d_in, const int* in_sizes, int n_in,
                              void* d_out, int out_size, void* d_ws, size_t ws_size,
                              hipStream_t stream) {
    const float* x  = (const float*)d_in[0];
    const int*   ei = (const int*)d_in[1];
    const float* W1 = (const float*)d_in[2];
    const float* b1 = (const float*)d_in[3];
    const float* W2 = (const float*)d_in[4];
    const float* b2 = (const float*)d_in[5];
    const float* P  = (const float*)d_in[6];
    const float* K  = (const float*)d_in[7];
    const float* U  = (const float*)d_in[8];
    float* out = (float*)d_out;

    int n = in_sizes[0] / IN_DIM;   // 100000
    int e = in_sizes[1] / 2;        // 1600000
    const int* src = ei;
    const int* dst = ei + e;

    // workspace layout:
    // cnt[n] | dinv[n] | off[n+1] | cursor[n] | bsum[1024] | ccur[512] | sorted[e]
    //   | hw1 fp16 [n*64] | agg1 f32 [n*64];   pairs (int2[e]) overlays agg1
    int*    cnt    = (int*)d_ws;
    float*  dinv   = (float*)(cnt + n);
    int*    off    = (int*)(dinv + n);
    int*    cursor = off + (n + 1);
    int*    bsum   = cursor + n;
    int*    ccur   = bsum + 1024;
    int*    sorted = ccur + 512;
    __half* hw1    = (__half*)(sorted + e);
    float*  agg1   = (float*)(hw1 + (size_t)n * HID);
    __half* hw2    = hw1;                 // reuse hw1 slot
    int2*   pairs  = (int2*)agg1;         // overlay: dead before gather1 writes agg1

    int nb   = (n + 1023) / 1024;         // scan blocks (98)
    int nbuk = (n + (1 << GRP_SH) - 1) >> GRP_SH;   // 391 coarse buckets

    hipMemsetAsync(cnt, 0, (size_t)n * sizeof(int), stream);
    count_k<<<(e + 255) / 256, 256, 0, stream>>>(dst, e, cnt);
    dinv_k<<<(n + 255) / 256, 256, 0, stream>>>(cnt, dinv, n);
    scan_local<<<nb, 256, 0, stream>>>(cnt, n, off, bsum);
    scan_bsum<<<1, 1024, 0, stream>>>(bsum, nb, n, off);
    scan_add<<<(n + 255) / 256, 256, 0, stream>>>(off, bsum, n, cursor);
    init_ccur<<<(nbuk + 255) / 256, 256, 0, stream>>>(off, n, nbuk, ccur);
    coarse_bin<<<(e + CB_TILE - 1) / CB_TILE, 256, 0, stream>>>(src, dst, e, nbuk,
                                                                ccur, pairs);
    fine_bin<<<nbuk, 256, 0, stream>>>(pairs, off, n, cursor, sorted);

    gemm1<<<(n + 31) / 32, 256, 0, stream>>>(x, W1, hw1, n);
    gather1<<<(n + 3) / 4, 256, 0, stream>>>(hw1, dinv, off, sorted, agg1, n);
    gemm2<<<(n + 31) / 32, 256, 0, stream>>>(agg1, W2, b1, hw2, n);
    gather2_fin<<<(n + 3) / 4, 256, 0, stream>>>(hw2, dinv, off, sorted,
                                                 b2, P, K, U, out, n);
}

// Round 10
// 257.712 us; speedup vs baseline: 2.5337x; 1.3069x over previous
//
#include <hip/hip_runtime.h>
#include <hip/hip_bf16.h>
#include <hip/hip_fp16.h>

#define IN_DIM 128
#define HID    64
#define OUT_DIM 40
#define GRP_SH 8                  // 256 nodes per coarse bucket
#define CB_TILE 4096              // edges per coarse block

// ---------------- coarse count: ccnt[b] = #edges with dst in bucket b --------
__global__ __launch_bounds__(256) void coarse_count(const int* __restrict__ dst, int e,
                                                    int nbuk, int* __restrict__ ccnt) {
    __shared__ int lcnt[512];
    int t = threadIdx.x;
    for (int i = t; i < nbuk; i += 256) lcnt[i] = 0;
    __syncthreads();
    int base = blockIdx.x * CB_TILE;
#pragma unroll
    for (int q = 0; q < 16; ++q) {
        int i = base + q * 256 + t;
        if (i < e) atomicAdd(&lcnt[dst[i] >> GRP_SH], 1);
    }
    __syncthreads();
    for (int i = t; i < nbuk; i += 256)
        if (lcnt[i]) atomicAdd(&ccnt[i], lcnt[i]);
}

// ---------------- scan of 391 coarse counts (1 block) ----------------
__global__ void scan_coarse(const int* __restrict__ ccnt, int nbuk, int e, int n,
                            int* __restrict__ cbase, int* __restrict__ ccur,
                            int* __restrict__ off) {
    __shared__ int tmp[512];
    int t = threadIdx.x;
    int v = (t < nbuk) ? ccnt[t] : 0;
    tmp[t] = v;
    __syncthreads();
    for (int ofs = 1; ofs < 512; ofs <<= 1) {
        int a = (t >= ofs) ? tmp[t - ofs] : 0;
        __syncthreads();
        tmp[t] += a;
        __syncthreads();
    }
    if (t < nbuk) { int ex = tmp[t] - v; cbase[t] = ex; ccur[t] = ex; }
    if (t == 0) { cbase[nbuk] = e; off[n] = e; }
}

// ---------------- coarse bin: edges -> pairs grouped by dst>>8 ----------------
__global__ __launch_bounds__(256) void coarse_bin(const int* __restrict__ src,
                                                  const int* __restrict__ dst, int e,
                                                  int nbuk, int* __restrict__ ccur,
                                                  int2* __restrict__ pairs) {
    __shared__ int lcnt[512];
    __shared__ int gbase[512];
    int t = threadIdx.x;
    for (int i = t; i < nbuk; i += 256) lcnt[i] = 0;
    __syncthreads();
    int base = blockIdx.x * CB_TILE;
    int s[16], d[16];
#pragma unroll
    for (int q = 0; q < 16; ++q) {
        int i = base + q * 256 + t;
        if (i < e) { s[q] = src[i]; d[q] = dst[i]; }
        else d[q] = -1;
    }
#pragma unroll
    for (int q = 0; q < 16; ++q)
        if (d[q] >= 0) atomicAdd(&lcnt[d[q] >> GRP_SH], 1);
    __syncthreads();
    for (int b = t; b < nbuk; b += 256) {
        int c = lcnt[b];
        gbase[b] = c ? atomicAdd(&ccur[b], c) : 0;
        lcnt[b] = 0;
    }
    __syncthreads();
#pragma unroll
    for (int q = 0; q < 16; ++q) {
        if (d[q] >= 0) {
            int b = d[q] >> GRP_SH;
            int slot = atomicAdd(&lcnt[b], 1);
            pairs[gbase[b] + slot] = make_int2(s[q], d[q]);
        }
    }
}

// ---------------- fine bin: block b owns bucket b entirely --------------------
// LDS histogram -> local scan -> write off+dinv -> scatter sorted.
__global__ __launch_bounds__(256) void fine_bin2(const int2* __restrict__ pairs,
                                                 const int* __restrict__ cbase, int n,
                                                 int* __restrict__ off,
                                                 float* __restrict__ dinv,
                                                 int* __restrict__ sorted) {
    __shared__ int hist[256];
    __shared__ int lpre[256];
    int b = blockIdx.x, t = threadIdx.x;
    int nlo = b << GRP_SH;
    int nnodes = min(256, n - nlo);
    int lo = cbase[b], hi = cbase[b + 1];
    hist[t] = 0;
    __syncthreads();
    for (int j = lo + t; j < hi; j += 256)
        atomicAdd(&hist[pairs[j].y - nlo], 1);
    __syncthreads();
    int v = hist[t];
    lpre[t] = v;
    __syncthreads();
    for (int ofs = 1; ofs < 256; ofs <<= 1) {
        int a = (t >= ofs) ? lpre[t - ofs] : 0;
        __syncthreads();
        lpre[t] += a;
        __syncthreads();
    }
    int excl = lpre[t] - v;
    if (t < nnodes) {
        off[nlo + t]  = lo + excl;
        dinv[nlo + t] = rsqrtf((float)v + 1.0f);
    }
    __syncthreads();
    hist[t] = lo + excl;            // reuse as global cursor
    __syncthreads();
    for (int j = lo + t; j < hi; j += 256) {
        int2 p = pairs[j];
        int pos = atomicAdd(&hist[p.y - nlo], 1);
        sorted[pos] = p.x;
    }
}

// ---------------- GEMM1: hw1 = fp16(x @ W1), register-blocked ----------------
__global__ __launch_bounds__(256) void gemm1(const float* __restrict__ x,
                                             const float* __restrict__ W1,
                                             __half* __restrict__ hw1, int n) {
    __shared__ float Ws[IN_DIM][HID];    // 32 KB
    __shared__ float xs[32][IN_DIM];     // 16 KB
    int tid = threadIdx.x;
    for (int i = tid * 4; i < IN_DIM * HID; i += 256 * 4)
        *(float4*)&Ws[0][i] = *(const float4*)&W1[i];
    int base = blockIdx.x * 32;
    for (int i = tid; i < 32 * IN_DIM / 4; i += 256) {
        int r = i >> 5, kk = i & 31;
        int gr = base + r;
        float4 v = {0.f, 0.f, 0.f, 0.f};
        if (gr < n) v = *(const float4*)&x[(size_t)gr * IN_DIM + kk * 4];
        *(float4*)&xs[r][kk * 4] = v;
    }
    __syncthreads();
    int col = tid & 63;
    int rg  = (tid >> 6) * 8;
    float acc[8] = {};
#pragma unroll 2
    for (int k = 0; k < IN_DIM; k += 4) {
        float w0 = Ws[k + 0][col], w1 = Ws[k + 1][col];
        float w2 = Ws[k + 2][col], w3 = Ws[k + 3][col];
#pragma unroll
        for (int r = 0; r < 8; ++r) {
            float4 xv = *(float4*)&xs[rg + r][k];
            acc[r] = fmaf(xv.x, w0, acc[r]);
            acc[r] = fmaf(xv.y, w1, acc[r]);
            acc[r] = fmaf(xv.z, w2, acc[r]);
            acc[r] = fmaf(xv.w, w3, acc[r]);
        }
    }
#pragma unroll
    for (int r = 0; r < 8; ++r) {
        int gr = base + rg + r;
        if (gr < n) hw1[(size_t)gr * HID + col] = __float2half(acc[r]);
    }
}

// ---- gather1: h[d] = fp16(relu(dinv^2*hw1[d] + sum norm*hw1[src] + b1)) -----
// half2 layout: 2 lane-groups of 32 -> 2 edges per wave-instruction.
__global__ void gather1_h2(const __half* __restrict__ hw1, const float* __restrict__ dinv,
                           const int* __restrict__ off, const int* __restrict__ sorted,
                           const float* __restrict__ b1, __half* __restrict__ hout,
                           int n) {
    int wid  = blockIdx.x * (blockDim.x >> 6) + (threadIdx.x >> 6);
    int lane = threadIdx.x & 63;
    if (wid >= n) return;
    int g = lane >> 5;          // edge group 0/1
    int c = lane & 31;          // column pair: cols 2c, 2c+1
    float dd = dinv[wid];
    float2 acc = {0.f, 0.f};
    if (g == 0) {
        __half2 hv = *(const __half2*)(hw1 + (size_t)wid * HID + 2 * c);
        acc.x = dd * dd * __low2float(hv);
        acc.y = dd * dd * __high2float(hv);
    }
    int j = off[wid], en = off[wid + 1];
    for (; j + 8 <= en; j += 8) {           // 4 pairs = 8 edges
        int s0 = sorted[j + 0 + g], s1 = sorted[j + 2 + g];
        int s2 = sorted[j + 4 + g], s3 = sorted[j + 6 + g];
        float w0 = dinv[s0] * dd, w1 = dinv[s1] * dd;
        float w2 = dinv[s2] * dd, w3 = dinv[s3] * dd;
        __half2 v0 = *(const __half2*)(hw1 + (size_t)s0 * HID + 2 * c);
        __half2 v1 = *(const __half2*)(hw1 + (size_t)s1 * HID + 2 * c);
        __half2 v2 = *(const __half2*)(hw1 + (size_t)s2 * HID + 2 * c);
        __half2 v3 = *(const __half2*)(hw1 + (size_t)s3 * HID + 2 * c);
        acc.x = fmaf(w0, __low2float(v0), acc.x);
        acc.y = fmaf(w0, __high2float(v0), acc.y);
        acc.x = fmaf(w1, __low2float(v1), acc.x);
        acc.y = fmaf(w1, __high2float(v1), acc.y);
        acc.x = fmaf(w2, __low2float(v2), acc.x);
        acc.y = fmaf(w2, __high2float(v2), acc.y);
        acc.x = fmaf(w3, __low2float(v3), acc.x);
        acc.y = fmaf(w3, __high2float(v3), acc.y);
    }
    for (; j + 2 <= en; j += 2) {           // 1 pair
        int s = sorted[j + g];
        float w = dinv[s] * dd;
        __half2 v = *(const __half2*)(hw1 + (size_t)s * HID + 2 * c);
        acc.x = fmaf(w, __low2float(v), acc.x);
        acc.y = fmaf(w, __high2float(v), acc.y);
    }
    if (j < en && g == 0) {                 // odd leftover, group 0 only
        int s = sorted[j];
        float w = dinv[s] * dd;
        __half2 v = *(const __half2*)(hw1 + (size_t)s * HID + 2 * c);
        acc.x = fmaf(w, __low2float(v), acc.x);
        acc.y = fmaf(w, __high2float(v), acc.y);
    }
    acc.x += __shfl_xor(acc.x, 32);
    acc.y += __shfl_xor(acc.y, 32);
    if (g == 0) {
        float2 bv = *(const float2*)&b1[2 * c];
        float rx = fmaxf(acc.x + bv.x, 0.f);
        float ry = fmaxf(acc.y + bv.y, 0.f);
        *(__half2*)(hout + (size_t)wid * HID + 2 * c) = __floats2half2_rn(rx, ry);
    }
}

// ---------------- GEMM2: hw2 = fp16(h @ W2), h already relu'd fp16 -----------
__global__ __launch_bounds__(256) void gemm2(const __half* __restrict__ h,
                                             const float* __restrict__ W2,
                                             __half* __restrict__ hw2, int n) {
    __shared__ float Ws[HID][64];        // cols 40..63 = 0
    __shared__ float hs[32][HID];
    int tid = threadIdx.x;
    for (int i = tid; i < HID * 64; i += 256) {
        int k = i >> 6, ccol = i & 63;
        Ws[k][ccol] = (ccol < OUT_DIM) ? W2[k * OUT_DIM + ccol] : 0.f;
    }
    int base = blockIdx.x * 32;
    {   // stage h tile: each thread converts 8 halves (16 B load)
        int r  = tid >> 3;
        int k0 = (tid & 7) * 8;
        int gr = base + r;
        float4 lofl = {0,0,0,0}, hifl = {0,0,0,0};
        if (gr < n) {
            uint4 u = *(const uint4*)(h + (size_t)gr * HID + k0);
            __half2* hp = (__half2*)&u;
            lofl = make_float4(__low2float(hp[0]), __high2float(hp[0]),
                               __low2float(hp[1]), __high2float(hp[1]));
            hifl = make_float4(__low2float(hp[2]), __high2float(hp[2]),
                               __low2float(hp[3]), __high2float(hp[3]));
        }
        *(float4*)&hs[r][k0]     = lofl;
        *(float4*)&hs[r][k0 + 4] = hifl;
    }
    __syncthreads();
    int col = tid & 63;
    int rg  = (tid >> 6) * 8;
    float acc[8] = {};
#pragma unroll 2
    for (int k = 0; k < HID; k += 4) {
        float w0 = Ws[k + 0][col], w1 = Ws[k + 1][col];
        float w2 = Ws[k + 2][col], w3 = Ws[k + 3][col];
#pragma unroll
        for (int r = 0; r < 8; ++r) {
            float4 hv = *(float4*)&hs[rg + r][k];
            acc[r] = fmaf(hv.x, w0, acc[r]);
            acc[r] = fmaf(hv.y, w1, acc[r]);
            acc[r] = fmaf(hv.z, w2, acc[r]);
            acc[r] = fmaf(hv.w, w3, acc[r]);
        }
    }
    if (col < OUT_DIM) {
#pragma unroll
        for (int r = 0; r < 8; ++r) {
            int gr = base + rg + r;
            if (gr < n) hw2[(size_t)gr * OUT_DIM + col] = __float2half(acc[r]);
        }
    }
}

// ---------------- gather2 + finalize ----------------
__global__ void gather2_fin(const __half* __restrict__ hw2, const float* __restrict__ dinv,
                            const int* __restrict__ off, const int* __restrict__ sorted,
                            const float* __restrict__ b2, const float* __restrict__ P,
                            const float* __restrict__ Kv, const float* __restrict__ U,
                            float* __restrict__ out, int n) {
    int wid  = blockIdx.x * (blockDim.x >> 6) + (threadIdx.x >> 6);
    int lane = threadIdx.x & 63;
    if (wid >= n) return;
    float dd = dinv[wid];
    int cl = (lane < OUT_DIM) ? lane : 0;
    float acc = dd * dd * __half2float(hw2[(size_t)wid * OUT_DIM + cl]);
    int j = off[wid], en = off[wid + 1];
    for (; j + 8 <= en; j += 8) {
        int ss[8]; float ww[8], vv[8];
#pragma unroll
        for (int q = 0; q < 8; ++q) ss[q] = sorted[j + q];
#pragma unroll
        for (int q = 0; q < 8; ++q) ww[q] = dinv[ss[q]];
#pragma unroll
        for (int q = 0; q < 8; ++q) vv[q] = __half2float(hw2[(size_t)ss[q] * OUT_DIM + cl]);
#pragma unroll
        for (int q = 0; q < 8; ++q) acc = fmaf(dd * ww[q], vv[q], acc);
    }
    for (; j + 4 <= en; j += 4) {
        int s0 = sorted[j + 0], s1 = sorted[j + 1];
        int s2 = sorted[j + 2], s3 = sorted[j + 3];
        float w0 = dinv[s0], w1 = dinv[s1], w2 = dinv[s2], w3 = dinv[s3];
        float v0 = __half2float(hw2[(size_t)s0 * OUT_DIM + cl]);
        float v1 = __half2float(hw2[(size_t)s1 * OUT_DIM + cl]);
        float v2 = __half2float(hw2[(size_t)s2 * OUT_DIM + cl]);
        float v3 = __half2float(hw2[(size_t)s3 * OUT_DIM + cl]);
        acc = fmaf(dd * w0, v0, acc);
        acc = fmaf(dd * w1, v1, acc);
        acc = fmaf(dd * w2, v2, acc);
        acc = fmaf(dd * w3, v3, acc);
    }
    for (; j < en; ++j) {
        int s = sorted[j];
        acc = fmaf(dd * dinv[s], __half2float(hw2[(size_t)s * OUT_DIM + cl]), acc);
    }
    float v = 0.f, y = -INFINITY;
    if (lane < OUT_DIM) {
        v = fmaxf(acc + b2[lane] + P[lane] * Kv[lane] * U[lane], 0.f);
        y = v;
    }
    float m = y;
#pragma unroll
    for (int o = 32; o; o >>= 1) m = fmaxf(m, __shfl_xor(m, o));
    float ex = (lane < OUT_DIM) ? __expf(v - m) : 0.f;
    float s2 = ex;
#pragma unroll
    for (int o = 32; o; o >>= 1) s2 += __shfl_xor(s2, o);
    float lse = m + __logf(s2);
    if (lane < OUT_DIM) out[(size_t)wid * OUT_DIM + lane] = v - lse;
}

extern "C" void kernel_launch(void* const* d_in, const int* in_sizes, int n_in,
                              void* d_out, int out_size, void* d_ws, size_t ws_size,
                              hipStream_t stream) {
    const float* x  = (const float*)d_in[0];
    const int*   ei = (const int*)d_in[1];
    const float* W1 = (const float*)d_in[2];
    const float* b1 = (const float*)d_in[3];
    const float* W2 = (const float*)d_in[4];
    const float* b2 = (const float*)d_in[5];
    const float* P  = (const float*)d_in[6];
    const float* K  = (const float*)d_in[7];
    const float* U  = (const float*)d_in[8];
    float* out = (float*)d_out;

    int n = in_sizes[0] / IN_DIM;   // 100000
    int e = in_sizes[1] / 2;        // 1600000
    const int* src = ei;
    const int* dst = ei + e;

    // workspace:
    // ccnt[512] | cbase[512] | ccur[512] | off[n+1] | dinv[n] | sorted[e]
    //   | hw1 fp16[n*64] | h fp16[n*64]   (pairs int2[e] overlays h: e*8 == n*128)
    int*    ccnt   = (int*)d_ws;
    int*    cbase  = ccnt + 512;
    int*    ccur   = cbase + 512;
    int*    off    = ccur + 512;
    float*  dinv   = (float*)(off + n + 1);
    int*    sorted = (int*)(dinv + n);
    __half* hw1    = (__half*)(sorted + e);
    __half* h      = hw1 + (size_t)n * HID;
    int2*   pairs  = (int2*)h;            // dead before gather1 writes h
    __half* hw2    = hw1;                 // reuse hw1 slot after gather1

    int nbuk = (n + (1 << GRP_SH) - 1) >> GRP_SH;   // 391

    hipMemsetAsync(ccnt, 0, 512 * sizeof(int), stream);
    coarse_count<<<(e + CB_TILE - 1) / CB_TILE, 256, 0, stream>>>(dst, e, nbuk, ccnt);
    scan_coarse<<<1, 512, 0, stream>>>(ccnt, nbuk, e, n, cbase, ccur, off);
    coarse_bin<<<(e + CB_TILE - 1) / CB_TILE, 256, 0, stream>>>(src, dst, e, nbuk,
                                                                ccur, pairs);
    fine_bin2<<<nbuk, 256, 0, stream>>>(pairs, cbase, n, off, dinv, sorted);

    gemm1<<<(n + 31) / 32, 256, 0, stream>>>(x, W1, hw1, n);
    gather1_h2<<<(n + 3) / 4, 256, 0, stream>>>(hw1, dinv, off, sorted, b1, h, n);
    gemm2<<<(n + 31) / 32, 256, 0, stream>>>(h, W2, hw2, n);
    gather2_fin<<<(n + 3) / 4, 256, 0, stream>>>(hw2, dinv, off, sorted,
                                                 b2, P, K, U, out, n);
}

// Round 11
// 252.206 us; speedup vs baseline: 2.5890x; 1.0218x over previous
//
#include <hip/hip_runtime.h>
#include <hip/hip_bf16.h>
#include <hip/hip_fp16.h>

#define IN_DIM 128
#define HID    64
#define OUT_DIM 40
#define GRP_SH 8                  // 256 nodes per coarse bucket
#define CB_TILE 4096              // edges per coarse block

// ---------------- coarse count: ccnt[b] = #edges with dst in bucket b --------
__global__ __launch_bounds__(256) void coarse_count(const int* __restrict__ dst, int e,
                                                    int nbuk, int* __restrict__ ccnt) {
    __shared__ int lcnt[512];
    int t = threadIdx.x;
    for (int i = t; i < nbuk; i += 256) lcnt[i] = 0;
    __syncthreads();
    int base = blockIdx.x * CB_TILE;
#pragma unroll
    for (int q = 0; q < 16; ++q) {
        int i = base + q * 256 + t;
        if (i < e) atomicAdd(&lcnt[dst[i] >> GRP_SH], 1);
    }
    __syncthreads();
    for (int i = t; i < nbuk; i += 256)
        if (lcnt[i]) atomicAdd(&ccnt[i], lcnt[i]);
}

// ---------------- scan of 391 coarse counts (1 block) ----------------
__global__ void scan_coarse(const int* __restrict__ ccnt, int nbuk, int e, int n,
                            int* __restrict__ cbase, int* __restrict__ ccur,
                            int* __restrict__ off) {
    __shared__ int tmp[512];
    int t = threadIdx.x;
    int v = (t < nbuk) ? ccnt[t] : 0;
    tmp[t] = v;
    __syncthreads();
    for (int ofs = 1; ofs < 512; ofs <<= 1) {
        int a = (t >= ofs) ? tmp[t - ofs] : 0;
        __syncthreads();
        tmp[t] += a;
        __syncthreads();
    }
    if (t < nbuk) { int ex = tmp[t] - v; cbase[t] = ex; ccur[t] = ex; }
    if (t == 0) { cbase[nbuk] = e; off[n] = e; }
}

// ---------------- coarse bin: edges -> pairs grouped by dst>>8 ----------------
__global__ __launch_bounds__(256) void coarse_bin(const int* __restrict__ src,
                                                  const int* __restrict__ dst, int e,
                                                  int nbuk, int* __restrict__ ccur,
                                                  int2* __restrict__ pairs) {
    __shared__ int lcnt[512];
    __shared__ int gbase[512];
    int t = threadIdx.x;
    for (int i = t; i < nbuk; i += 256) lcnt[i] = 0;
    __syncthreads();
    int base = blockIdx.x * CB_TILE;
    int s[16], d[16];
#pragma unroll
    for (int q = 0; q < 16; ++q) {
        int i = base + q * 256 + t;
        if (i < e) { s[q] = src[i]; d[q] = dst[i]; }
        else d[q] = -1;
    }
#pragma unroll
    for (int q = 0; q < 16; ++q)
        if (d[q] >= 0) atomicAdd(&lcnt[d[q] >> GRP_SH], 1);
    __syncthreads();
    for (int b = t; b < nbuk; b += 256) {
        int c = lcnt[b];
        gbase[b] = c ? atomicAdd(&ccur[b], c) : 0;
        lcnt[b] = 0;
    }
    __syncthreads();
#pragma unroll
    for (int q = 0; q < 16; ++q) {
        if (d[q] >= 0) {
            int b = d[q] >> GRP_SH;
            int slot = atomicAdd(&lcnt[b], 1);
            pairs[gbase[b] + slot] = make_int2(s[q], d[q]);
        }
    }
}

// ---------------- fine bin: block b owns bucket b entirely --------------------
__global__ __launch_bounds__(256) void fine_bin2(const int2* __restrict__ pairs,
                                                 const int* __restrict__ cbase, int n,
                                                 int* __restrict__ off,
                                                 float* __restrict__ dinv,
                                                 int* __restrict__ sorted) {
    __shared__ int hist[256];
    __shared__ int lpre[256];
    int b = blockIdx.x, t = threadIdx.x;
    int nlo = b << GRP_SH;
    int nnodes = min(256, n - nlo);
    int lo = cbase[b], hi = cbase[b + 1];
    hist[t] = 0;
    __syncthreads();
    for (int j = lo + t; j < hi; j += 256)
        atomicAdd(&hist[pairs[j].y - nlo], 1);
    __syncthreads();
    int v = hist[t];
    lpre[t] = v;
    __syncthreads();
    for (int ofs = 1; ofs < 256; ofs <<= 1) {
        int a = (t >= ofs) ? lpre[t - ofs] : 0;
        __syncthreads();
        lpre[t] += a;
        __syncthreads();
    }
    int excl = lpre[t] - v;
    if (t < nnodes) {
        off[nlo + t]  = lo + excl;
        dinv[nlo + t] = rsqrtf((float)v + 1.0f);
    }
    __syncthreads();
    hist[t] = lo + excl;            // reuse as global cursor
    __syncthreads();
    for (int j = lo + t; j < hi; j += 256) {
        int2 p = pairs[j];
        int pos = atomicAdd(&hist[p.y - nlo], 1);
        sorted[pos] = p.x;
    }
}

// ---------------- GEMM1: hw1 = fp16(x @ W1), register-blocked ----------------
__global__ __launch_bounds__(256) void gemm1(const float* __restrict__ x,
                                             const float* __restrict__ W1,
                                             __half* __restrict__ hw1, int n) {
    __shared__ float Ws[IN_DIM][HID];    // 32 KB
    __shared__ float xs[32][IN_DIM];     // 16 KB
    int tid = threadIdx.x;
    for (int i = tid * 4; i < IN_DIM * HID; i += 256 * 4)
        *(float4*)&Ws[0][i] = *(const float4*)&W1[i];
    int base = blockIdx.x * 32;
    for (int i = tid; i < 32 * IN_DIM / 4; i += 256) {
        int r = i >> 5, kk = i & 31;
        int gr = base + r;
        float4 v = {0.f, 0.f, 0.f, 0.f};
        if (gr < n) v = *(const float4*)&x[(size_t)gr * IN_DIM + kk * 4];
        *(float4*)&xs[r][kk * 4] = v;
    }
    __syncthreads();
    int col = tid & 63;
    int rg  = (tid >> 6) * 8;
    float acc[8] = {};
#pragma unroll 2
    for (int k = 0; k < IN_DIM; k += 4) {
        float w0 = Ws[k + 0][col], w1 = Ws[k + 1][col];
        float w2 = Ws[k + 2][col], w3 = Ws[k + 3][col];
#pragma unroll
        for (int r = 0; r < 8; ++r) {
            float4 xv = *(float4*)&xs[rg + r][k];
            acc[r] = fmaf(xv.x, w0, acc[r]);
            acc[r] = fmaf(xv.y, w1, acc[r]);
            acc[r] = fmaf(xv.z, w2, acc[r]);
            acc[r] = fmaf(xv.w, w3, acc[r]);
        }
    }
#pragma unroll
    for (int r = 0; r < 8; ++r) {
        int gr = base + rg + r;
        if (gr < n) hw1[(size_t)gr * HID + col] = __float2half(acc[r]);
    }
}

// ---- gather1: h[d] = fp16(relu(dinv^2*hw1[d] + sum norm*hw1[src] + b1)) -----
// 4 edge-groups x 16 lanes; each lane owns 4 cols (uint2 = 4 halves, 8 B).
__global__ void gather1_h4(const __half* __restrict__ hw1, const float* __restrict__ dinv,
                           const int* __restrict__ off, const int* __restrict__ sorted,
                           const float* __restrict__ b1, __half* __restrict__ hout,
                           int n) {
    int wid  = blockIdx.x * (blockDim.x >> 6) + (threadIdx.x >> 6);
    int lane = threadIdx.x & 63;
    if (wid >= n) return;
    int g = lane >> 4;          // edge group 0..3
    int c = lane & 15;          // col quad: cols 4c..4c+3
    float dd = dinv[wid];
    float4 acc = {0.f, 0.f, 0.f, 0.f};
    if (g == 0) {
        uint2 u = *(const uint2*)(hw1 + (size_t)wid * HID + 4 * c);
        __half2 h0 = *(__half2*)&u.x, h1 = *(__half2*)&u.y;
        float s2 = dd * dd;
        acc.x = s2 * __low2float(h0);  acc.y = s2 * __high2float(h0);
        acc.z = s2 * __low2float(h1);  acc.w = s2 * __high2float(h1);
    }
    int j = off[wid], en = off[wid + 1];
    for (; j + 8 <= en; j += 8) {           // 2 batches x 4 edges
        int sa = sorted[j + g], sb = sorted[j + 4 + g];
        float wa = dinv[sa] * dd, wb = dinv[sb] * dd;
        uint2 ua = *(const uint2*)(hw1 + (size_t)sa * HID + 4 * c);
        uint2 ub = *(const uint2*)(hw1 + (size_t)sb * HID + 4 * c);
        __half2 a0 = *(__half2*)&ua.x, a1 = *(__half2*)&ua.y;
        __half2 b0 = *(__half2*)&ub.x, b1h = *(__half2*)&ub.y;
        acc.x = fmaf(wa, __low2float(a0), acc.x);
        acc.y = fmaf(wa, __high2float(a0), acc.y);
        acc.z = fmaf(wa, __low2float(a1), acc.z);
        acc.w = fmaf(wa, __high2float(a1), acc.w);
        acc.x = fmaf(wb, __low2float(b0), acc.x);
        acc.y = fmaf(wb, __high2float(b0), acc.y);
        acc.z = fmaf(wb, __low2float(b1h), acc.z);
        acc.w = fmaf(wb, __high2float(b1h), acc.w);
    }
    for (; j + 4 <= en; j += 4) {           // 1 batch x 4 edges
        int s = sorted[j + g];
        float w = dinv[s] * dd;
        uint2 u = *(const uint2*)(hw1 + (size_t)s * HID + 4 * c);
        __half2 h0 = *(__half2*)&u.x, h1 = *(__half2*)&u.y;
        acc.x = fmaf(w, __low2float(h0), acc.x);
        acc.y = fmaf(w, __high2float(h0), acc.y);
        acc.z = fmaf(w, __low2float(h1), acc.z);
        acc.w = fmaf(w, __high2float(h1), acc.w);
    }
    int rem = en - j;                        // 0..3
    if (g < rem) {
        int s = sorted[j + g];
        float w = dinv[s] * dd;
        uint2 u = *(const uint2*)(hw1 + (size_t)s * HID + 4 * c);
        __half2 h0 = *(__half2*)&u.x, h1 = *(__half2*)&u.y;
        acc.x = fmaf(w, __low2float(h0), acc.x);
        acc.y = fmaf(w, __high2float(h0), acc.y);
        acc.z = fmaf(w, __low2float(h1), acc.z);
        acc.w = fmaf(w, __high2float(h1), acc.w);
    }
    // reduce the 4 groups (xor 16 then 32)
    acc.x += __shfl_xor(acc.x, 16); acc.y += __shfl_xor(acc.y, 16);
    acc.z += __shfl_xor(acc.z, 16); acc.w += __shfl_xor(acc.w, 16);
    acc.x += __shfl_xor(acc.x, 32); acc.y += __shfl_xor(acc.y, 32);
    acc.z += __shfl_xor(acc.z, 32); acc.w += __shfl_xor(acc.w, 32);
    if (g == 0) {
        float4 bb = *(const float4*)&b1[4 * c];
        float rx = fmaxf(acc.x + bb.x, 0.f);
        float ry = fmaxf(acc.y + bb.y, 0.f);
        float rz = fmaxf(acc.z + bb.z, 0.f);
        float rw = fmaxf(acc.w + bb.w, 0.f);
        union { __half2 h[2]; uint2 u; } st;
        st.h[0] = __floats2half2_rn(rx, ry);
        st.h[1] = __floats2half2_rn(rz, rw);
        *(uint2*)(hout + (size_t)wid * HID + 4 * c) = st.u;
    }
}

// ---------------- GEMM2: hw2 = fp16(h @ W2), h already relu'd fp16 -----------
__global__ __launch_bounds__(256) void gemm2(const __half* __restrict__ h,
                                             const float* __restrict__ W2,
                                             __half* __restrict__ hw2, int n) {
    __shared__ float Ws[HID][64];        // cols 40..63 = 0
    __shared__ float hs[32][HID];
    int tid = threadIdx.x;
    for (int i = tid; i < HID * 64; i += 256) {
        int k = i >> 6, ccol = i & 63;
        Ws[k][ccol] = (ccol < OUT_DIM) ? W2[k * OUT_DIM + ccol] : 0.f;
    }
    int base = blockIdx.x * 32;
    {
        int r  = tid >> 3;
        int k0 = (tid & 7) * 8;
        int gr = base + r;
        float4 lofl = {0,0,0,0}, hifl = {0,0,0,0};
        if (gr < n) {
            uint4 u = *(const uint4*)(h + (size_t)gr * HID + k0);
            __half2* hp = (__half2*)&u;
            lofl = make_float4(__low2float(hp[0]), __high2float(hp[0]),
                               __low2float(hp[1]), __high2float(hp[1]));
            hifl = make_float4(__low2float(hp[2]), __high2float(hp[2]),
                               __low2float(hp[3]), __high2float(hp[3]));
        }
        *(float4*)&hs[r][k0]     = lofl;
        *(float4*)&hs[r][k0 + 4] = hifl;
    }
    __syncthreads();
    int col = tid & 63;
    int rg  = (tid >> 6) * 8;
    float acc[8] = {};
#pragma unroll 2
    for (int k = 0; k < HID; k += 4) {
        float w0 = Ws[k + 0][col], w1 = Ws[k + 1][col];
        float w2 = Ws[k + 2][col], w3 = Ws[k + 3][col];
#pragma unroll
        for (int r = 0; r < 8; ++r) {
            float4 hv = *(float4*)&hs[rg + r][k];
            acc[r] = fmaf(hv.x, w0, acc[r]);
            acc[r] = fmaf(hv.y, w1, acc[r]);
            acc[r] = fmaf(hv.z, w2, acc[r]);
            acc[r] = fmaf(hv.w, w3, acc[r]);
        }
    }
    if (col < OUT_DIM) {
#pragma unroll
        for (int r = 0; r < 8; ++r) {
            int gr = base + rg + r;
            if (gr < n) hw2[(size_t)gr * OUT_DIM + col] = __float2half(acc[r]);
        }
    }
}

// ---------------- gather2 + finalize: 3 edge-groups x 20 half2 cols -----------
__global__ void gather2_fin(const __half* __restrict__ hw2, const float* __restrict__ dinv,
                            const int* __restrict__ off, const int* __restrict__ sorted,
                            const float* __restrict__ b2, const float* __restrict__ P,
                            const float* __restrict__ Kv, const float* __restrict__ U,
                            float* __restrict__ out, int n) {
    int wid  = blockIdx.x * (blockDim.x >> 6) + (threadIdx.x >> 6);
    int lane = threadIdx.x & 63;
    if (wid >= n) return;
    int g = lane / 20;          // 0..2 active, 3 = idle (lanes 60..63)
    int c = lane % 20;          // col pair: cols 2c, 2c+1
    bool act = lane < 60;
    float dd = dinv[wid];
    float2 acc = {0.f, 0.f};
    if (lane < 20) {
        __half2 hv = *(const __half2*)(hw2 + (size_t)wid * OUT_DIM + 2 * c);
        acc.x = dd * dd * __low2float(hv);
        acc.y = dd * dd * __high2float(hv);
    }
    int j = off[wid], en = off[wid + 1];
    for (; j + 6 <= en; j += 6) {           // 2 batches x 3 edges
        if (act) {
            int sa = sorted[j + g], sb = sorted[j + 3 + g];
            float wa = dinv[sa] * dd, wb = dinv[sb] * dd;
            __half2 va = *(const __half2*)(hw2 + (size_t)sa * OUT_DIM + 2 * c);
            __half2 vb = *(const __half2*)(hw2 + (size_t)sb * OUT_DIM + 2 * c);
            acc.x = fmaf(wa, __low2float(va), acc.x);
            acc.y = fmaf(wa, __high2float(va), acc.y);
            acc.x = fmaf(wb, __low2float(vb), acc.x);
            acc.y = fmaf(wb, __high2float(vb), acc.y);
        }
    }
    for (; j + 3 <= en; j += 3) {
        if (act) {
            int s = sorted[j + g];
            float w = dinv[s] * dd;
            __half2 v = *(const __half2*)(hw2 + (size_t)s * OUT_DIM + 2 * c);
            acc.x = fmaf(w, __low2float(v), acc.x);
            acc.y = fmaf(w, __high2float(v), acc.y);
        }
    }
    int rem = en - j;                        // 0..2
    if (act && g < rem) {
        int s = sorted[j + g];
        float w = dinv[s] * dd;
        __half2 v = *(const __half2*)(hw2 + (size_t)s * OUT_DIM + 2 * c);
        acc.x = fmaf(w, __low2float(v), acc.x);
        acc.y = fmaf(w, __high2float(v), acc.y);
    }
    // fold groups 1,2 into lanes 0..19
    float r1x = __shfl(acc.x, lane + 20), r1y = __shfl(acc.y, lane + 20);
    float r2x = __shfl(acc.x, lane + 40), r2y = __shfl(acc.y, lane + 40);
    float vx = 0.f, vy = 0.f, mym = -INFINITY;
    if (lane < 20) {
        acc.x += r1x + r2x;
        acc.y += r1y + r2y;
        float2 bb = *(const float2*)&b2[2 * c];
        float2 pp = *(const float2*)&P[2 * c];
        float2 kk = *(const float2*)&Kv[2 * c];
        float2 uu = *(const float2*)&U[2 * c];
        vx = fmaxf(acc.x + bb.x + pp.x * kk.x * uu.x, 0.f);
        vy = fmaxf(acc.y + bb.y + pp.y * kk.y * uu.y, 0.f);
        mym = fmaxf(vx, vy);
    }
    // 32-lane butterfly (lanes 20..31 hold neutral values)
    float m = mym;
#pragma unroll
    for (int o = 16; o; o >>= 1) m = fmaxf(m, __shfl_xor(m, o));
    float ex = (lane < 20) ? __expf(vx - m) + __expf(vy - m) : 0.f;
    float ssum = ex;
#pragma unroll
    for (int o = 16; o; o >>= 1) ssum += __shfl_xor(ssum, o);
    float lse = m + __logf(ssum);
    if (lane < 20)
        *(float2*)(out + (size_t)wid * OUT_DIM + 2 * c) = make_float2(vx - lse, vy - lse);
}

extern "C" void kernel_launch(void* const* d_in, const int* in_sizes, int n_in,
                              void* d_out, int out_size, void* d_ws, size_t ws_size,
                              hipStream_t stream) {
    const float* x  = (const float*)d_in[0];
    const int*   ei = (const int*)d_in[1];
    const float* W1 = (const float*)d_in[2];
    const float* b1 = (const float*)d_in[3];
    const float* W2 = (const float*)d_in[4];
    const float* b2 = (const float*)d_in[5];
    const float* P  = (const float*)d_in[6];
    const float* K  = (const float*)d_in[7];
    const float* U  = (const float*)d_in[8];
    float* out = (float*)d_out;

    int n = in_sizes[0] / IN_DIM;   // 100000
    int e = in_sizes[1] / 2;        // 1600000
    const int* src = ei;
    const int* dst = ei + e;

    // workspace:
    // ccnt[512] | cbase[512] | ccur[512] | off[n+1] | dinv[n] | sorted[e]
    //   | (16B-aligned) hw1 fp16[n*64] | h fp16[n*64]  (pairs int2[e] overlays h)
    int*    ccnt   = (int*)d_ws;
    int*    cbase  = ccnt + 512;
    int*    ccur   = cbase + 512;
    int*    off    = ccur + 512;
    float*  dinv   = (float*)(off + n + 1);
    int*    sorted = (int*)(dinv + n);
    __half* hw1    = (__half*)(((uintptr_t)(sorted + e) + 15) & ~(uintptr_t)15);
    __half* h      = hw1 + (size_t)n * HID;
    int2*   pairs  = (int2*)h;            // dead before gather1 writes h
    __half* hw2    = hw1;                 // reuse hw1 slot after gather1

    int nbuk = (n + (1 << GRP_SH) - 1) >> GRP_SH;   // 391

    hipMemsetAsync(ccnt, 0, 512 * sizeof(int), stream);
    coarse_count<<<(e + CB_TILE - 1) / CB_TILE, 256, 0, stream>>>(dst, e, nbuk, ccnt);
    scan_coarse<<<1, 512, 0, stream>>>(ccnt, nbuk, e, n, cbase, ccur, off);
    coarse_bin<<<(e + CB_TILE - 1) / CB_TILE, 256, 0, stream>>>(src, dst, e, nbuk,
                                                                ccur, pairs);
    fine_bin2<<<nbuk, 256, 0, stream>>>(pairs, cbase, n, off, dinv, sorted);

    gemm1<<<(n + 31) / 32, 256, 0, stream>>>(x, W1, hw1, n);
    gather1_h4<<<(n + 3) / 4, 256, 0, stream>>>(hw1, dinv, off, sorted, b1, h, n);
    gemm2<<<(n + 31) / 32, 256, 0, stream>>>(h, W2, hw2, n);
    gather2_fin<<<(n + 3) / 4, 256, 0, stream>>>(hw2, dinv, off, sorted,
                                                 b2, P, K, U, out, n);
}